// Round 1
// baseline (2254.307 us; speedup 1.0000x reference)
//
#include <hip/hip_runtime.h>
#include <hip/hip_bf16.h>
#include <cstdint>
#include <cstddef>

// Problem constants (B,T,C,H) = (4,512,2048,32), N=64
#define BB 4
#define TT 512
#define CC 2048
#define HH 32
#define NN 64
#define BT (BB*TT)     // 2048 rows for all GEMMs
#define DMIX 32
#define DDEC 64
static constexpr float EPSV = 1e-5f * 64.0f;  // 1e-5 * 8^2

// ---------------------------------------------------------------------------
// Generic f32 SGEMM: C[M,N] = epi(A[M,K] @ B[K,N] (+bias))
// EPI: 0=none, 1=silu, 2=tanh, 3=exp(-exp(v + bias[n]))
// Requires M%BM==0, N%BN==0, K%BK==0 (true for every call below).
// ---------------------------------------------------------------------------
template<int BM,int BN,int BK,int TM,int TN,int EPI>
__global__ __launch_bounds__((BM/TM)*(BN/TN))
void sgemm(const float* __restrict__ A, const float* __restrict__ B,
           float* __restrict__ Cd, int M, int N, int K,
           int lda, int ldb, int ldc, const float* __restrict__ bias)
{
    constexpr int NT = (BM/TM)*(BN/TN);
    __shared__ float As[BK][BM + 4];   // +4 pad: conflict-free transpose store
    __shared__ float Bs[BK][BN];
    const int tid = threadIdx.x;
    const int m0 = blockIdx.y * BM;
    const int n0 = blockIdx.x * BN;
    const int rm = tid / (BN/TN);
    const int rn = tid % (BN/TN);

    float acc[TM][TN];
#pragma unroll
    for (int i = 0; i < TM; ++i)
#pragma unroll
        for (int j = 0; j < TN; ++j) acc[i][j] = 0.f;

    for (int k0 = 0; k0 < K; k0 += BK) {
#pragma unroll
        for (int p = 0; p < (BM*BK)/NT; ++p) {
            int i  = tid + p*NT;
            int m  = i / BK, kk = i % BK;
            As[kk][m] = A[(size_t)(m0+m)*lda + (k0+kk)];
        }
#pragma unroll
        for (int p = 0; p < (BK*BN)/NT; ++p) {
            int i  = tid + p*NT;
            int kk = i / BN, n = i % BN;
            Bs[kk][n] = B[(size_t)(k0+kk)*ldb + (n0+n)];
        }
        __syncthreads();
#pragma unroll
        for (int kk = 0; kk < BK; ++kk) {
            float a[TM], bb[TN];
#pragma unroll
            for (int i = 0; i < TM; ++i) a[i] = As[kk][rm*TM+i];
#pragma unroll
            for (int j = 0; j < TN; ++j) bb[j] = Bs[kk][rn*TN+j];
#pragma unroll
            for (int i = 0; i < TM; ++i)
#pragma unroll
                for (int j = 0; j < TN; ++j)
                    acc[i][j] = fmaf(a[i], bb[j], acc[i][j]);
        }
        __syncthreads();
    }

#pragma unroll
    for (int i = 0; i < TM; ++i) {
        int m = m0 + rm*TM + i;
#pragma unroll
        for (int j = 0; j < TN; ++j) {
            int n = n0 + rn*TN + j;
            float v = acc[i][j];
            if constexpr (EPI == 1) { v = v / (1.f + expf(-v)); }       // silu
            else if constexpr (EPI == 2) { v = tanhf(v); }
            else if constexpr (EPI == 3) { v = expf(-expf(v + bias[n])); } // decay
            Cd[(size_t)m*ldc + n] = v;
        }
    }
}

// ---------------------------------------------------------------------------
// Prep: dxprev = shifted(x) - x ; xin = x + dxprev*maa_x
// ---------------------------------------------------------------------------
__global__ __launch_bounds__(256)
void prep_kernel(const float* __restrict__ x, const float* __restrict__ shift,
                 const float* __restrict__ maa_x,
                 float* __restrict__ dxprev, float* __restrict__ xin)
{
    size_t idx = (size_t)blockIdx.x*256 + threadIdx.x;     // over B*T*C
    int c = (int)(idx % CC);
    size_t bt = idx / CC;
    int t = (int)(bt % TT);
    int b = (int)(bt / TT);
    float xv = x[idx];
    float prev = t ? x[idx - CC] : shift[(size_t)b*CC + c];
    float dx = prev - xv;
    dxprev[idx] = dx;
    xin[idx] = fmaf(dx, maa_x[c], xv);
}

// xw..xg currently hold mix_f; transform in place: x + dxprev*(maa_f + mix_f)
__global__ __launch_bounds__(256)
void mixapply_kernel(const float* __restrict__ x, const float* __restrict__ dx,
                     const float* __restrict__ mW, const float* __restrict__ mK,
                     const float* __restrict__ mV, const float* __restrict__ mR,
                     const float* __restrict__ mG,
                     float* __restrict__ xw, float* __restrict__ xk,
                     float* __restrict__ xv, float* __restrict__ xr,
                     float* __restrict__ xg)
{
    size_t idx = (size_t)blockIdx.x*256 + threadIdx.x;
    int c = (int)(idx % CC);
    float xval = x[idx], d = dx[idx];
    xw[idx] = fmaf(d, mW[c] + xw[idx], xval);
    xk[idx] = fmaf(d, mK[c] + xk[idx], xval);
    xv[idx] = fmaf(d, mV[c] + xv[idx], xval);
    xr[idx] = fmaf(d, mR[c] + xr[idx], xval);
    xg[idx] = fmaf(d, mG[c] + xg[idx], xval);
}

// ---------------------------------------------------------------------------
// WKV6 scan. One block per (b,h). 256 threads = 4 waves.
// Thread (wave w, lane j) owns state s[i][j] for i in [16w, 16w+16).
// ---------------------------------------------------------------------------
__global__ __launch_bounds__(256)
void wkv_kernel(const float* __restrict__ r, const float* __restrict__ k,
                const float* __restrict__ v, const float* __restrict__ d,
                const float* __restrict__ u, const float* __restrict__ s0,
                float* __restrict__ y)
{
    int bh = blockIdx.x;
    int b = bh / HH, h = bh % HH;
    int tid = threadIdx.x;
    int lane = tid & 63;
    int wv = tid >> 6;
    int i0 = wv * 16;

    __shared__ float rs[NN], ks[NN], vs[NN], ds[NN], us[NN], part[4][NN];

    if (tid < NN) us[tid] = u[h*NN + tid];

    float s[16];
    const float* sp = s0 + ((size_t)(b*HH + h))*NN*NN;
#pragma unroll
    for (int ii = 0; ii < 16; ++ii) s[ii] = sp[(size_t)(i0+ii)*NN + lane];

    size_t base = (size_t)b*TT*CC + (size_t)h*NN;
    for (int t = 0; t < TT; ++t) {
        size_t off = base + (size_t)t*CC;
        __syncthreads();                 // protects rs..ds (and us on t=0, part reads)
        if (tid < 64)        rs[tid]       = r[off + tid];
        else if (tid < 128)  ks[tid - 64]  = k[off + (tid - 64)];
        else if (tid < 192)  vs[tid - 128] = v[off + (tid - 128)];
        else                 ds[tid - 192] = d[off + (tid - 192)];
        __syncthreads();

        float vj = vs[lane];
        float yp = 0.f;
#pragma unroll
        for (int ii = 0; ii < 16; ++ii) {
            float kv = ks[i0+ii] * vj;
            yp += rs[i0+ii] * fmaf(us[i0+ii], kv, s[ii]);   // uses pre-update s
            s[ii] = fmaf(ds[i0+ii], s[ii], kv);
        }
        part[wv][lane] = yp;
        __syncthreads();
        if (wv == 0) {
            y[off + lane] = part[0][lane] + part[1][lane] + part[2][lane] + part[3][lane];
        }
    }
}

// ---------------------------------------------------------------------------
// GroupNorm over N=64 per (b,t,h), then *ln_g + ln_b, then * g (silu'd gate)
// One wave per head-row, 4 waves per block.
// ---------------------------------------------------------------------------
__global__ __launch_bounds__(256)
void gnorm_kernel(const float* __restrict__ y, const float* __restrict__ g,
                  const float* __restrict__ ln_g, const float* __restrict__ ln_b,
                  float* __restrict__ yg)
{
    int gidx = blockIdx.x*4 + (threadIdx.x >> 6);  // (b*T)*H + h
    int lane = threadIdx.x & 63;
    int h = gidx % HH;
    int bt = gidx / HH;
    size_t idx = (size_t)bt*CC + (size_t)h*NN + lane;

    float val = y[idx];
    float sum = val, sq = val*val;
#pragma unroll
    for (int m = 1; m < 64; m <<= 1) {
        sum += __shfl_xor(sum, m, 64);
        sq  += __shfl_xor(sq,  m, 64);
    }
    float mean = sum * (1.f/64.f);
    float var  = sq  * (1.f/64.f) - mean*mean;
    float nv = (val - mean) * rsqrtf(var + EPSV);
    int c = h*NN + lane;
    yg[idx] = (nv * ln_g[c] + ln_b[c]) * g[idx];
}

__global__ __launch_bounds__(256)
void shiftout_kernel(const float* __restrict__ x, float* __restrict__ o)
{
    int i = blockIdx.x*256 + threadIdx.x;  // B*C = 8192
    int b = i / CC, c = i % CC;
    o[i] = x[((size_t)b*TT + (TT-1))*CC + c];
}

// ---------------------------------------------------------------------------
extern "C" void kernel_launch(void* const* d_in, const int* in_sizes, int n_in,
                              void* d_out, int out_size, void* d_ws, size_t ws_size,
                              hipStream_t stream)
{
    const float* x          = (const float*)d_in[0];
    const float* shift_st   = (const float*)d_in[1];
    const float* wkv_state  = (const float*)d_in[2];
    const float* maa_x      = (const float*)d_in[3];
    const float* maa_w      = (const float*)d_in[4];
    const float* maa_k      = (const float*)d_in[5];
    const float* maa_v      = (const float*)d_in[6];
    const float* maa_r      = (const float*)d_in[7];
    const float* maa_g      = (const float*)d_in[8];
    const float* maa_w1     = (const float*)d_in[9];
    const float* maa_w2     = (const float*)d_in[10];
    const float* time_decay = (const float*)d_in[11];
    const float* decay_w1   = (const float*)d_in[12];
    const float* decay_w2   = (const float*)d_in[13];
    const float* time_faaaa = (const float*)d_in[14];
    const float* Wr         = (const float*)d_in[15];
    const float* Wk         = (const float*)d_in[16];
    const float* Wv         = (const float*)d_in[17];
    const float* Wg         = (const float*)d_in[18];
    const float* Wo         = (const float*)d_in[19];
    const float* ln_g       = (const float*)d_in[20];
    const float* ln_b       = (const float*)d_in[21];

    // Workspace slots (16.78 MB each). Aliasing plan:
    // s0: dxprev -> k      s1: xin -> r        s2: mixw->xw -> y
    // s3: mixk->xk -> yg   s4: mixv->xv        s5: mixr->xr -> v
    // s6: mixg->xg         s7: g               s8: decay
    // s9: xxx (2048*160) + wtmp (2048*64)
    float* ws = (float*)d_ws;
    const size_t SL = (size_t)BT*CC;
    float* s0 = ws;
    float* s1 = ws + 1*SL;
    float* s2 = ws + 2*SL;
    float* s3 = ws + 3*SL;
    float* s4 = ws + 4*SL;
    float* s5 = ws + 5*SL;
    float* s6 = ws + 6*SL;
    float* s7 = ws + 7*SL;
    float* s8 = ws + 8*SL;
    float* xxx  = ws + 9*SL;
    float* wtmp = xxx + (size_t)BT*160;

    float* out       = (float*)d_out;
    float* out_shift = out + SL;                    // B*C
    float* out_state = out_shift + (size_t)BB*CC;   // B*H*N*N

    const int EW_GRID = (int)(SL/256);

    // 1) prep + trivial outputs
    prep_kernel<<<EW_GRID, 256, 0, stream>>>(x, shift_st, maa_x, s0, s1);
    shiftout_kernel<<<BB*CC/256, 256, 0, stream>>>(x, out_shift);
    hipMemcpyAsync(out_state, wkv_state, (size_t)BB*HH*NN*NN*sizeof(float),
                   hipMemcpyDeviceToDevice, stream);

    // 2) xxx = tanh(xin @ maa_w1)   (2048 x 160, K=2048)
    {
        dim3 g(160/32, BT/64);
        sgemm<64,32,16,2,4,2><<<g, 256, 0, stream>>>(s1, maa_w1, xxx,
            BT, 160, CC, CC, 160, 160, nullptr);
    }

    // 3) mix_f = xxx_f @ maa_w2[f]  (K=32), then in-place xw..xg
    {
        float* mixs[5] = {s2, s3, s4, s5, s6};
        dim3 g(CC/128, BT/128);
        for (int f = 0; f < 5; ++f) {
            sgemm<128,128,16,8,8,0><<<g, 256, 0, stream>>>(
                xxx + f*DMIX, maa_w2 + (size_t)f*DMIX*CC, mixs[f],
                BT, CC, DMIX, 160, CC, CC, nullptr);
        }
        mixapply_kernel<<<EW_GRID, 256, 0, stream>>>(x, s0,
            maa_w, maa_k, maa_v, maa_r, maa_g, s2, s3, s4, s5, s6);
    }

    // 4) wtmp = tanh(xw @ decay_w1) (2048 x 64, K=2048)
    {
        dim3 g(DDEC/32, BT/64);
        sgemm<64,32,16,2,4,2><<<g, 256, 0, stream>>>(s2, decay_w1, wtmp,
            BT, DDEC, CC, CC, DDEC, DDEC, nullptr);
    }
    // 5) decay = exp(-exp(wtmp @ decay_w2 + time_decay))  (K=64)
    {
        dim3 g(CC/128, BT/128);
        sgemm<128,128,16,8,8,3><<<g, 256, 0, stream>>>(wtmp, decay_w2, s8,
            BT, CC, DDEC, DDEC, CC, CC, time_decay);
    }

    // 6) big GEMMs (order matters for slot aliasing)
    dim3 gg(CC/128, BT/128);
    sgemm<128,128,16,8,8,0><<<gg, 256, 0, stream>>>(s5, Wr, s1, BT, CC, CC, CC, CC, CC, nullptr); // r
    sgemm<128,128,16,8,8,0><<<gg, 256, 0, stream>>>(s4, Wv, s5, BT, CC, CC, CC, CC, CC, nullptr); // v
    sgemm<128,128,16,8,8,0><<<gg, 256, 0, stream>>>(s3, Wk, s0, BT, CC, CC, CC, CC, CC, nullptr); // k
    sgemm<128,128,16,8,8,1><<<gg, 256, 0, stream>>>(s6, Wg, s7, BT, CC, CC, CC, CC, CC, nullptr); // g (silu)

    // 7) sequential WKV scan: y -> s2
    wkv_kernel<<<BB*HH, 256, 0, stream>>>(s1, s0, s5, s8, time_faaaa, wkv_state, s2);

    // 8) groupnorm + gate: yg -> s3
    gnorm_kernel<<<BB*TT*HH/4, 256, 0, stream>>>(s2, s7, ln_g, ln_b, s3);

    // 9) out = yg @ Wo
    sgemm<128,128,16,8,8,0><<<gg, 256, 0, stream>>>(s3, Wo, out, BT, CC, CC, CC, CC, CC, nullptr);
}

// Round 2
// 987.388 us; speedup vs baseline: 2.2831x; 2.2831x over previous
//
#include <hip/hip_runtime.h>
#include <hip/hip_bf16.h>
#include <cstdint>
#include <cstddef>

// Problem constants (B,T,C,H) = (4,512,2048,32), N=64
#define BB 4
#define TT 512
#define CC 2048
#define HH 32
#define NN 64
#define BT (BB*TT)     // 2048 rows for all GEMMs
#define DMIX 32
#define DDEC 64
static constexpr float EPSV = 1e-5f * 64.0f;  // 1e-5 * 8^2

typedef __attribute__((ext_vector_type(8))) short bf16x8;
typedef __attribute__((ext_vector_type(4))) float f32x4;

// ---------------------------------------------------------------------------
// async global->LDS, 16B per lane. LDS dest must be wave-uniform base;
// lane i lands at base + i*16.
// ---------------------------------------------------------------------------
__device__ __forceinline__ void gload16(const void* g, void* l) {
    __builtin_amdgcn_global_load_lds(
        (const __attribute__((address_space(1))) unsigned int*)g,
        (__attribute__((address_space(3))) unsigned int*)l, 16, 0, 0);
}

// ---------------------------------------------------------------------------
// bf16 MFMA GEMM, m97 structure: 128x128 tile, BK=32, 4 waves (2x2),
// each wave 64x64 = 4x4 frags of 16x16x32. A: MxK row-major bf16.
// Bt: NxK row-major bf16 (pre-transposed weight). C: f32 row-major ld=2048.
// EPI: 0=none, 1=silu
// ---------------------------------------------------------------------------
template<int EPI>
__global__ __launch_bounds__(256)
void mm_bf16(const __hip_bfloat16* __restrict__ A, const __hip_bfloat16* __restrict__ Bt,
             float* __restrict__ C, int K)
{
    __shared__ __hip_bfloat16 As[128][32];
    __shared__ __hip_bfloat16 Bs[128][32];
    const int tid = threadIdx.x, wid = tid >> 6, lane = tid & 63;
    const int m0 = blockIdx.y * 128, n0 = blockIdx.x * 128;
    const int wr = wid >> 1, wc = wid & 1;

    f32x4 acc[4][4] = {};

    // staging geometry: lane i covers row wid*16 + i/4, cols (i%4)*8..+8
    const int srow = wid*16 + (lane >> 2);
    const int scol = (lane & 3) * 8;
    const __hip_bfloat16* aSrc = A  + (size_t)(m0 + srow)*K + scol;
    const __hip_bfloat16* bSrc = Bt + (size_t)(n0 + srow)*K + scol;
    __hip_bfloat16* aDst0 = &As[wid*16][0];
    __hip_bfloat16* aDst1 = &As[64 + wid*16][0];
    __hip_bfloat16* bDst0 = &Bs[wid*16][0];
    __hip_bfloat16* bDst1 = &Bs[64 + wid*16][0];

    const int fr = lane & 15;
    const int kg = (lane >> 4) * 8;

    for (int k0 = 0; k0 < K; k0 += 32) {
        gload16(aSrc + k0,                 aDst0);
        gload16(aSrc + (size_t)64*K + k0,  aDst1);
        gload16(bSrc + k0,                 bDst0);
        gload16(bSrc + (size_t)64*K + k0,  bDst1);
        __syncthreads();   // drains vmcnt before use (compiler-inserted)
        bf16x8 af[4], bf[4];
#pragma unroll
        for (int m = 0; m < 4; ++m)
            af[m] = *(const bf16x8*)&As[wr*64 + m*16 + fr][kg];
#pragma unroll
        for (int n = 0; n < 4; ++n)
            bf[n] = *(const bf16x8*)&Bs[wc*64 + n*16 + fr][kg];
#pragma unroll
        for (int m = 0; m < 4; ++m)
#pragma unroll
            for (int n = 0; n < 4; ++n)
                acc[m][n] = __builtin_amdgcn_mfma_f32_16x16x32_bf16(
                                af[m], bf[n], acc[m][n], 0, 0, 0);
        __syncthreads();
    }

    // C/D layout: col = lane&15, row = (lane>>4)*4 + reg   [m89]
    const int rg = (lane >> 4) * 4;
#pragma unroll
    for (int m = 0; m < 4; ++m) {
#pragma unroll
        for (int n = 0; n < 4; ++n) {
#pragma unroll
            for (int rI = 0; rI < 4; ++rI) {
                int row = m0 + wr*64 + m*16 + rg + rI;
                int col = n0 + wc*64 + n*16 + fr;
                float v = acc[m][n][rI];
                if constexpr (EPI == 1) v = v / (1.f + expf(-v));
                C[(size_t)row*CC + col] = v;
            }
        }
    }
}

// ---------------------------------------------------------------------------
// Weight transpose + cast: W[K][N] f32 -> Wt[N][K] bf16. 64x64 tiles.
// ---------------------------------------------------------------------------
__global__ __launch_bounds__(256)
void transpose_cast(const float* __restrict__ W, __hip_bfloat16* __restrict__ Wt,
                    int K, int N)
{
    __shared__ float tile[64][65];
    const int kb = blockIdx.y * 64, nb = blockIdx.x * 64;
    const int tr = threadIdx.x >> 6, tc = threadIdx.x & 63;
#pragma unroll
    for (int p = 0; p < 16; ++p)
        tile[tr + p*4][tc] = W[(size_t)(kb + tr + p*4)*N + nb + tc];
    __syncthreads();
#pragma unroll
    for (int p = 0; p < 16; ++p)
        Wt[(size_t)(nb + tr + p*4)*K + kb + tc] =
            __float2bfloat16(tile[tc][tr + p*4]);
}

// ---------------------------------------------------------------------------
// Generic f32 SGEMM (kept for skinny GEMMs). EPI: 0=none, 2=tanh,
// 3=exp(-exp(v + bias[n]))
// ---------------------------------------------------------------------------
template<int BM,int BN,int BK,int TM,int TN,int EPI>
__global__ __launch_bounds__((BM/TM)*(BN/TN))
void sgemm(const float* __restrict__ A, const float* __restrict__ B,
           float* __restrict__ Cd, int M, int N, int K,
           int lda, int ldb, int ldc, const float* __restrict__ bias)
{
    constexpr int NT = (BM/TM)*(BN/TN);
    __shared__ float As[BK][BM + 4];
    __shared__ float Bs[BK][BN];
    const int tid = threadIdx.x;
    const int m0 = blockIdx.y * BM;
    const int n0 = blockIdx.x * BN;
    const int rm = tid / (BN/TN);
    const int rn = tid % (BN/TN);

    float acc[TM][TN];
#pragma unroll
    for (int i = 0; i < TM; ++i)
#pragma unroll
        for (int j = 0; j < TN; ++j) acc[i][j] = 0.f;

    for (int k0 = 0; k0 < K; k0 += BK) {
#pragma unroll
        for (int p = 0; p < (BM*BK)/NT; ++p) {
            int i  = tid + p*NT;
            int m  = i / BK, kk = i % BK;
            As[kk][m] = A[(size_t)(m0+m)*lda + (k0+kk)];
        }
#pragma unroll
        for (int p = 0; p < (BK*BN)/NT; ++p) {
            int i  = tid + p*NT;
            int kk = i / BN, n = i % BN;
            Bs[kk][n] = B[(size_t)(k0+kk)*ldb + (n0+n)];
        }
        __syncthreads();
#pragma unroll
        for (int kk = 0; kk < BK; ++kk) {
            float a[TM], bb[TN];
#pragma unroll
            for (int i = 0; i < TM; ++i) a[i] = As[kk][rm*TM+i];
#pragma unroll
            for (int j = 0; j < TN; ++j) bb[j] = Bs[kk][rn*TN+j];
#pragma unroll
            for (int i = 0; i < TM; ++i)
#pragma unroll
                for (int j = 0; j < TN; ++j)
                    acc[i][j] = fmaf(a[i], bb[j], acc[i][j]);
        }
        __syncthreads();
    }

#pragma unroll
    for (int i = 0; i < TM; ++i) {
        int m = m0 + rm*TM + i;
#pragma unroll
        for (int j = 0; j < TN; ++j) {
            int n = n0 + rn*TN + j;
            float v = acc[i][j];
            if constexpr (EPI == 2) { v = tanhf(v); }
            else if constexpr (EPI == 3) { v = expf(-expf(v + bias[n])); }
            Cd[(size_t)m*ldc + n] = v;
        }
    }
}

// ---------------------------------------------------------------------------
// Prep: dxprev = shifted(x) - x ; xin = x + dxprev*maa_x
// ---------------------------------------------------------------------------
__global__ __launch_bounds__(256)
void prep_kernel(const float* __restrict__ x, const float* __restrict__ shift,
                 const float* __restrict__ maa_x,
                 float* __restrict__ dxprev, float* __restrict__ xin)
{
    size_t idx = (size_t)blockIdx.x*256 + threadIdx.x;
    int c = (int)(idx % CC);
    size_t bt = idx / CC;
    int t = (int)(bt % TT);
    int b = (int)(bt / TT);
    float xv = x[idx];
    float prev = t ? x[idx - CC] : shift[(size_t)b*CC + c];
    float dx = prev - xv;
    dxprev[idx] = dx;
    xin[idx] = fmaf(dx, maa_x[c], xv);
}

// ---------------------------------------------------------------------------
// Fused: mix_f = xxx[:,f,:] @ maa_w2[f]  (K=32 each), then
// xf = x + dx*(maa_f + mix_f). Writes xw f32 (in-place over dx) and
// xk/xv/xr/xg directly as bf16 for the MFMA GEMMs.
// Block: 64 c-cols x 128 bt-rows; 256 thr = (tc 0..63, tb 0..3).
// ---------------------------------------------------------------------------
__global__ __launch_bounds__(256)
void fusedmix_kernel(const float* __restrict__ xxx, const float* __restrict__ w2,
                     const float* __restrict__ x, const float* dx,
                     const float* __restrict__ maa_w, const float* __restrict__ maa_k,
                     const float* __restrict__ maa_v, const float* __restrict__ maa_r,
                     const float* __restrict__ maa_g,
                     float* xw, __hip_bfloat16* __restrict__ xk,
                     __hip_bfloat16* __restrict__ xv2, __hip_bfloat16* __restrict__ xr,
                     __hip_bfloat16* __restrict__ xg)
{
    __shared__ float w2s[160][64];
    const int c0 = blockIdx.x * 64, bt0 = blockIdx.y * 128;
    const int tid = threadIdx.x;
    const int tc = tid & 63, tb = tid >> 6;
    for (int idx = tid; idx < 160*64; idx += 256) {
        int kk = idx >> 6, cc = idx & 63;
        w2s[kk][cc] = w2[(size_t)kk*CC + c0 + cc];
    }
    __syncthreads();
    const int c = c0 + tc;
    const float mw_c = maa_w[c], mk_c = maa_k[c], mv_c = maa_v[c];
    const float mr_c = maa_r[c], mg_c = maa_g[c];
    for (int it = 0; it < 32; ++it) {
        int bt = bt0 + it*4 + tb;
        const float* xrow = xxx + (size_t)bt*160;
        float a0=0,a1=0,a2=0,a3=0,a4=0;
#pragma unroll
        for (int d2 = 0; d2 < 32; ++d2) {
            a0 = fmaf(xrow[d2],       w2s[d2][tc],       a0);
            a1 = fmaf(xrow[32+d2],    w2s[32+d2][tc],    a1);
            a2 = fmaf(xrow[64+d2],    w2s[64+d2][tc],    a2);
            a3 = fmaf(xrow[96+d2],    w2s[96+d2][tc],    a3);
            a4 = fmaf(xrow[128+d2],   w2s[128+d2][tc],   a4);
        }
        size_t idx = (size_t)bt*CC + c;
        float xval = x[idx], dv = dx[idx];
        xw[idx]  = fmaf(dv, mw_c + a0, xval);   // in-place over dx (same idx)
        xk[idx]  = __float2bfloat16(fmaf(dv, mk_c + a1, xval));
        xv2[idx] = __float2bfloat16(fmaf(dv, mv_c + a2, xval));
        xr[idx]  = __float2bfloat16(fmaf(dv, mr_c + a3, xval));
        xg[idx]  = __float2bfloat16(fmaf(dv, mg_c + a4, xval));
    }
}

// ---------------------------------------------------------------------------
// WKV6 scan, barrier-free. One block per (b,h), 4 waves.
// Wave w privately owns output columns j in [16w,16w+16); lane handles
// column j = 16w + (lane&15) for rows i0..i0+15, i0 = (lane>>4)*16.
// Each wave stages its own {r,k,d, r*u*k} broadcast copy in private LDS.
// ---------------------------------------------------------------------------
__global__ __launch_bounds__(256)
void wkv_kernel(const float* __restrict__ r, const float* __restrict__ k,
                const float* __restrict__ v, const float* __restrict__ d,
                const float* __restrict__ u, const float* __restrict__ s0,
                float* __restrict__ y)
{
    const int bh = blockIdx.x;
    const int b = bh >> 5, h = bh & 31;
    const int wv = threadIdx.x >> 6, lane = threadIdx.x & 63;
    const int j  = wv*16 + (lane & 15);
    const int i0 = (lane >> 4) * 16;

    __shared__ float4 rkdw[4][64];   // wave-private: [wave][i] = {r,k,d,r*u*k}

    float s[16];
    const float* sp = s0 + (size_t)bh*NN*NN;
#pragma unroll
    for (int ii = 0; ii < 16; ++ii) s[ii] = sp[(size_t)(i0+ii)*NN + j];

    const float ul = u[h*NN + lane];

    const size_t base = (size_t)b*TT*CC + (size_t)h*NN;
    float rr = r[base + lane], kk = k[base + lane];
    float dd = d[base + lane], vv = v[base + j];

    for (int t = 0; t < TT; ++t) {
        size_t off = base + (size_t)t*CC;
        rkdw[wv][lane] = make_float4(rr, kk, dd, rr*ul*kk);
        float vj = vv;
        if (t + 1 < TT) {                       // prefetch next step
            size_t off2 = off + CC;
            rr = r[off2 + lane]; kk = k[off2 + lane];
            dd = d[off2 + lane]; vv = v[off2 + j];
        }
        float yp = 0.f, sv = 0.f;
#pragma unroll
        for (int ii = 0; ii < 16; ++ii) {
            float4 q = rkdw[wv][i0 + ii];       // uniform per 16-lane group
            yp = fmaf(q.x, s[ii], yp);
            sv += q.w;
            s[ii] = fmaf(q.z, s[ii], q.y * vj);
        }
        float yj = fmaf(sv, vj, yp);
        yj += __shfl_xor(yj, 16);
        yj += __shfl_xor(yj, 32);
        if (lane < 16) y[off + wv*16 + lane] = yj;
    }
}

// ---------------------------------------------------------------------------
// GroupNorm over N=64 per (b,t,h) + affine + gate; emits bf16 for Wo GEMM.
// ---------------------------------------------------------------------------
__global__ __launch_bounds__(256)
void gnorm_kernel(const float* __restrict__ y, const float* __restrict__ g,
                  const float* __restrict__ ln_g, const float* __restrict__ ln_b,
                  __hip_bfloat16* __restrict__ yg)
{
    int gidx = blockIdx.x*4 + (threadIdx.x >> 6);
    int lane = threadIdx.x & 63;
    int h = gidx % HH;
    int bt = gidx / HH;
    size_t idx = (size_t)bt*CC + (size_t)h*NN + lane;

    float val = y[idx];
    float sum = val, sq = val*val;
#pragma unroll
    for (int m = 1; m < 64; m <<= 1) {
        sum += __shfl_xor(sum, m, 64);
        sq  += __shfl_xor(sq,  m, 64);
    }
    float mean = sum * (1.f/64.f);
    float var  = sq  * (1.f/64.f) - mean*mean;
    float nv = (val - mean) * rsqrtf(var + EPSV);
    int c = h*NN + lane;
    yg[idx] = __float2bfloat16((nv * ln_g[c] + ln_b[c]) * g[idx]);
}

__global__ __launch_bounds__(256)
void shiftout_kernel(const float* __restrict__ x, float* __restrict__ o)
{
    int i = blockIdx.x*256 + threadIdx.x;  // B*C = 8192
    int b = i / CC, c = i % CC;
    o[i] = x[((size_t)b*TT + (TT-1))*CC + c];
}

// ---------------------------------------------------------------------------
extern "C" void kernel_launch(void* const* d_in, const int* in_sizes, int n_in,
                              void* d_out, int out_size, void* d_ws, size_t ws_size,
                              hipStream_t stream)
{
    const float* x          = (const float*)d_in[0];
    const float* shift_st   = (const float*)d_in[1];
    const float* wkv_state  = (const float*)d_in[2];
    const float* maa_x      = (const float*)d_in[3];
    const float* maa_w      = (const float*)d_in[4];
    const float* maa_k      = (const float*)d_in[5];
    const float* maa_v      = (const float*)d_in[6];
    const float* maa_r      = (const float*)d_in[7];
    const float* maa_g      = (const float*)d_in[8];
    const float* maa_w1     = (const float*)d_in[9];
    const float* maa_w2     = (const float*)d_in[10];
    const float* time_decay = (const float*)d_in[11];
    const float* decay_w1   = (const float*)d_in[12];
    const float* decay_w2   = (const float*)d_in[13];
    const float* time_faaaa = (const float*)d_in[14];
    const float* Wr         = (const float*)d_in[15];
    const float* Wk         = (const float*)d_in[16];
    const float* Wv         = (const float*)d_in[17];
    const float* Wg         = (const float*)d_in[18];
    const float* Wo         = (const float*)d_in[19];
    const float* ln_g       = (const float*)d_in[20];
    const float* ln_b       = (const float*)d_in[21];

    // f32 slots (16.78 MB each), aliased:
    //   fA: dxprev -> xw -> y      fB: xin -> decay
    //   fC: r   fD: k   fE: v   fF: g
    float* ws = (float*)d_ws;
    const size_t SL = (size_t)BT*CC;
    float* fA = ws;
    float* fB = fA + SL;
    float* fC = fB + SL;
    float* fD = fC + SL;
    float* fE = fD + SL;
    float* fF = fE + SL;
    float* xxx  = fF + SL;                    // 2048*160 f32
    float* wtmp = xxx + (size_t)BT*160;       // 2048*64 f32
    // bf16 region (8.39 MB per 2048x2048 slot)
    __hip_bfloat16* hbase = (__hip_bfloat16*)(wtmp + (size_t)BT*DDEC);
    const size_t HL = (size_t)CC*CC;
    __hip_bfloat16* WrT = hbase;
    __hip_bfloat16* WkT = WrT + HL;
    __hip_bfloat16* WvT = WkT + HL;
    __hip_bfloat16* WgT = WvT + HL;
    __hip_bfloat16* WoT = WgT + HL;
    __hip_bfloat16* bxr = WoT + HL;
    __hip_bfloat16* bxk = bxr + HL;
    __hip_bfloat16* bxv = bxk + HL;
    __hip_bfloat16* bxg = bxv + HL;
    __hip_bfloat16* byg = bxg + HL;

    float* out       = (float*)d_out;
    float* out_shift = out + SL;
    float* out_state = out_shift + (size_t)BB*CC;

    const int EW_GRID = (int)(SL/256);
    dim3 tg(CC/64, CC/64);      // transpose grid
    dim3 gg(CC/128, BT/128);    // 128x128 tile grids

    // 0) weight transposes (independent)
    transpose_cast<<<tg, 256, 0, stream>>>(Wr, WrT, CC, CC);
    transpose_cast<<<tg, 256, 0, stream>>>(Wk, WkT, CC, CC);
    transpose_cast<<<tg, 256, 0, stream>>>(Wv, WvT, CC, CC);
    transpose_cast<<<tg, 256, 0, stream>>>(Wg, WgT, CC, CC);
    transpose_cast<<<tg, 256, 0, stream>>>(Wo, WoT, CC, CC);

    // 1) prep + trivial outputs
    prep_kernel<<<EW_GRID, 256, 0, stream>>>(x, shift_st, maa_x, fA, fB);
    shiftout_kernel<<<BB*CC/256, 256, 0, stream>>>(x, out_shift);
    hipMemcpyAsync(out_state, wkv_state, (size_t)BB*HH*NN*NN*sizeof(float),
                   hipMemcpyDeviceToDevice, stream);

    // 2) xxx = tanh(xin @ maa_w1)   (2048 x 160, K=2048) f32
    {
        dim3 g(160/32, BT/64);
        sgemm<64,32,16,2,4,2><<<g, 256, 0, stream>>>(fB, maa_w1, xxx,
            BT, 160, CC, CC, 160, 160, nullptr);
    }

    // 3) fused mix (writes xw into fA in-place, bf16 xk/xv/xr/xg)
    {
        dim3 g(CC/64, BT/128);
        fusedmix_kernel<<<g, 256, 0, stream>>>(xxx, maa_w2, x, fA,
            maa_w, maa_k, maa_v, maa_r, maa_g, fA, bxk, bxv, bxr, bxg);
    }

    // 4) wtmp = tanh(xw @ decay_w1) (2048 x 64, K=2048) f32
    {
        dim3 g(DDEC/32, BT/64);
        sgemm<64,32,16,2,4,2><<<g, 256, 0, stream>>>(fA, decay_w1, wtmp,
            BT, DDEC, CC, CC, DDEC, DDEC, nullptr);
    }
    // 5) decay = exp(-exp(wtmp @ decay_w2 + time_decay))  (K=64) -> fB
    sgemm<128,128,16,8,8,3><<<gg, 256, 0, stream>>>(wtmp, decay_w2, fB,
        BT, CC, DDEC, DDEC, CC, CC, time_decay);

    // 6) big GEMMs via bf16 MFMA
    mm_bf16<0><<<gg, 256, 0, stream>>>(bxr, WrT, fC, CC);  // r
    mm_bf16<0><<<gg, 256, 0, stream>>>(bxk, WkT, fD, CC);  // k
    mm_bf16<0><<<gg, 256, 0, stream>>>(bxv, WvT, fE, CC);  // v
    mm_bf16<1><<<gg, 256, 0, stream>>>(bxg, WgT, fF, CC);  // g = silu

    // 7) WKV scan: y -> fA (xw dead after step 4)
    wkv_kernel<<<BB*HH, 256, 0, stream>>>(fC, fD, fE, fB, time_faaaa, wkv_state, fA);

    // 8) groupnorm + gate -> bf16 yg
    gnorm_kernel<<<BB*TT*HH/4, 256, 0, stream>>>(fA, fF, ln_g, ln_b, byg);

    // 9) out = yg @ Wo
    mm_bf16<0><<<gg, 256, 0, stream>>>(byg, WoT, out, CC);
}

// Round 3
// 816.588 us; speedup vs baseline: 2.7606x; 1.2092x over previous
//
#include <hip/hip_runtime.h>
#include <hip/hip_bf16.h>
#include <cstdint>
#include <cstddef>

// Problem constants (B,T,C,H) = (4,512,2048,32), N=64
#define BB 4
#define TT 512
#define CC 2048
#define HH 32
#define NN 64
#define BT (BB*TT)     // 2048 rows for all GEMMs
#define DMIX 32
#define DDEC 64
static constexpr float EPSV = 1e-5f * 64.0f;  // 1e-5 * 8^2

typedef __attribute__((ext_vector_type(8))) short bf16x8;
typedef __attribute__((ext_vector_type(4))) float f32x4;

// ---------------------------------------------------------------------------
// async global->LDS, 16B per lane: lane i lands at lds_base + i*16.
// ---------------------------------------------------------------------------
__device__ __forceinline__ void gload16(const void* g, void* l) {
    __builtin_amdgcn_global_load_lds(
        (const __attribute__((address_space(1))) unsigned int*)g,
        (__attribute__((address_space(3))) unsigned int*)l, 16, 0, 0);
}

// ---------------------------------------------------------------------------
// bf16 MFMA GEMM core. 128 x BN tile, BK=32, 4 waves (2x2), wave = 64 x BN/2.
// A: MxK row-major bf16 (lda=K). Bt: NxK row-major bf16 (pre-transposed).
// C: f32 row-major (ldc). epi: 0=none, 1=silu, 2=tanh.
// ---------------------------------------------------------------------------
template<int BN>
__device__ __forceinline__
void mm_core(const __hip_bfloat16* __restrict__ A, const __hip_bfloat16* __restrict__ Bt,
             float* __restrict__ C, int K, int ldc, int epi, int bx, int by)
{
    constexpr int NF = BN/32;                 // frags per wave in N
    __shared__ __hip_bfloat16 As[128][32];
    __shared__ __hip_bfloat16 Bs[BN][32];
    const int tid = threadIdx.x, wid = tid >> 6, lane = tid & 63;
    const int m0 = by * 128, n0 = bx * BN;
    const int wr = wid >> 1, wc = wid & 1;

    f32x4 acc[4][NF] = {};

    const int srow = wid*16 + (lane >> 2);
    const int scol = (lane & 3) * 8;
    const __hip_bfloat16* aSrc = A  + (size_t)(m0 + srow)*K + scol;
    const __hip_bfloat16* bSrc = Bt + (size_t)(n0 + srow)*K + scol;
    __hip_bfloat16* aDst0 = &As[wid*16][0];
    __hip_bfloat16* aDst1 = &As[64 + wid*16][0];
    __hip_bfloat16* bDst0 = &Bs[wid*16][0];

    const int fr = lane & 15;
    const int kg = (lane >> 4) * 8;

    for (int k0 = 0; k0 < K; k0 += 32) {
        gload16(aSrc + k0,                aDst0);
        gload16(aSrc + (size_t)64*K + k0, aDst1);
        gload16(bSrc + k0,                bDst0);
        if constexpr (BN == 128)
            gload16(bSrc + (size_t)64*K + k0, &Bs[64 + wid*16][0]);
        __syncthreads();
        bf16x8 af[4], bf[NF];
#pragma unroll
        for (int m = 0; m < 4; ++m)
            af[m] = *(const bf16x8*)&As[wr*64 + m*16 + fr][kg];
#pragma unroll
        for (int n = 0; n < NF; ++n)
            bf[n] = *(const bf16x8*)&Bs[wc*(BN/2) + n*16 + fr][kg];
#pragma unroll
        for (int m = 0; m < 4; ++m)
#pragma unroll
            for (int n = 0; n < NF; ++n)
                acc[m][n] = __builtin_amdgcn_mfma_f32_16x16x32_bf16(
                                af[m], bf[n], acc[m][n], 0, 0, 0);
        __syncthreads();
    }

    // C/D layout: col = lane&15, row = (lane>>4)*4 + reg   [m89]
    const int rg = (lane >> 4) * 4;
#pragma unroll
    for (int m = 0; m < 4; ++m) {
#pragma unroll
        for (int n = 0; n < NF; ++n) {
#pragma unroll
            for (int rI = 0; rI < 4; ++rI) {
                int row = m0 + wr*64 + m*16 + rg + rI;
                int col = n0 + wc*(BN/2) + n*16 + fr;
                float v = acc[m][n][rI];
                if (epi == 1)      v = v / (1.f + expf(-v));
                else if (epi == 2) v = tanhf(v);
                C[(size_t)row*ldc + col] = v;
            }
        }
    }
}

template<int BN, int EPI>
__global__ __launch_bounds__(256)
void mm_bf16(const __hip_bfloat16* __restrict__ A, const __hip_bfloat16* __restrict__ Bt,
             float* __restrict__ C, int K, int ldc)
{
    mm_core<BN>(A, Bt, C, K, ldc, EPI, blockIdx.x, blockIdx.y);
}

// z-batched: 4 independent GEMMs (r,k,v,g), z==3 applies silu.
__global__ __launch_bounds__(256)
void mm_bf16_b4(const __hip_bfloat16* A0, const __hip_bfloat16* A1,
                const __hip_bfloat16* A2, const __hip_bfloat16* A3,
                const __hip_bfloat16* B0, const __hip_bfloat16* B1,
                const __hip_bfloat16* B2, const __hip_bfloat16* B3,
                float* C0, float* C1, float* C2, float* C3, int K)
{
    int z = blockIdx.z;
    const __hip_bfloat16* A = (z==0)?A0:(z==1)?A1:(z==2)?A2:A3;
    const __hip_bfloat16* B = (z==0)?B0:(z==1)?B1:(z==2)?B2:B3;
    float* C = (z==0)?C0:(z==1)?C1:(z==2)?C2:C3;
    mm_core<128>(A, B, C, K, CC, (z==3)?1:0, blockIdx.x, blockIdx.y);
}

// ---------------------------------------------------------------------------
// Weight transpose + cast: W[K][N] f32 -> Wt[N][K] bf16. 64x64 tiles.
// ---------------------------------------------------------------------------
__global__ __launch_bounds__(256)
void transpose_cast(const float* __restrict__ W, __hip_bfloat16* __restrict__ Wt,
                    int K, int N)
{
    __shared__ float tile[64][65];
    const int kb = blockIdx.y * 64, nb = blockIdx.x * 64;
    const int tr = threadIdx.x >> 6, tc = threadIdx.x & 63;
#pragma unroll
    for (int p = 0; p < 16; ++p)
        tile[tr + p*4][tc] = W[(size_t)(kb + tr + p*4)*N + nb + tc];
    __syncthreads();
#pragma unroll
    for (int p = 0; p < 16; ++p)
        Wt[(size_t)(nb + tr + p*4)*K + kb + tc] =
            __float2bfloat16(tile[tc][tr + p*4]);
}

// Same but source has Nsrc cols; dest rows beyond Nsrc are zero (pad to grid).
__global__ __launch_bounds__(256)
void transpose_cast_pad(const float* __restrict__ W, __hip_bfloat16* __restrict__ Wt,
                        int K, int Nsrc)
{
    __shared__ float tile[64][65];
    const int kb = blockIdx.y * 64, nb = blockIdx.x * 64;
    const int tr = threadIdx.x >> 6, tc = threadIdx.x & 63;
#pragma unroll
    for (int p = 0; p < 16; ++p) {
        int col = nb + tc;
        tile[tr + p*4][tc] = (col < Nsrc) ?
            W[(size_t)(kb + tr + p*4)*Nsrc + col] : 0.f;
    }
    __syncthreads();
#pragma unroll
    for (int p = 0; p < 16; ++p)
        Wt[(size_t)(nb + tr + p*4)*K + kb + tc] =
            __float2bfloat16(tile[tc][tr + p*4]);
}

// ---------------------------------------------------------------------------
// Generic f32 SGEMM (skinny / decay path). EPI: 0=none, 2=tanh,
// 3=exp(-exp(v + bias[n]))
// ---------------------------------------------------------------------------
template<int BM,int BN,int BK,int TM,int TN,int EPI>
__global__ __launch_bounds__((BM/TM)*(BN/TN))
void sgemm(const float* __restrict__ A, const float* __restrict__ B,
           float* __restrict__ Cd, int M, int N, int K,
           int lda, int ldb, int ldc, const float* __restrict__ bias)
{
    constexpr int NT = (BM/TM)*(BN/TN);
    __shared__ float As[BK][BM + 4];
    __shared__ float Bs[BK][BN];
    const int tid = threadIdx.x;
    const int m0 = blockIdx.y * BM;
    const int n0 = blockIdx.x * BN;
    const int rm = tid / (BN/TN);
    const int rn = tid % (BN/TN);

    float acc[TM][TN];
#pragma unroll
    for (int i = 0; i < TM; ++i)
#pragma unroll
        for (int j = 0; j < TN; ++j) acc[i][j] = 0.f;

    for (int k0 = 0; k0 < K; k0 += BK) {
#pragma unroll
        for (int p = 0; p < (BM*BK)/NT; ++p) {
            int i  = tid + p*NT;
            int m  = i / BK, kk = i % BK;
            As[kk][m] = A[(size_t)(m0+m)*lda + (k0+kk)];
        }
#pragma unroll
        for (int p = 0; p < (BK*BN)/NT; ++p) {
            int i  = tid + p*NT;
            int kk = i / BN, n = i % BN;
            Bs[kk][n] = B[(size_t)(k0+kk)*ldb + (n0+n)];
        }
        __syncthreads();
#pragma unroll
        for (int kk = 0; kk < BK; ++kk) {
            float a[TM], bb[TN];
#pragma unroll
            for (int i = 0; i < TM; ++i) a[i] = As[kk][rm*TM+i];
#pragma unroll
            for (int j = 0; j < TN; ++j) bb[j] = Bs[kk][rn*TN+j];
#pragma unroll
            for (int i = 0; i < TM; ++i)
#pragma unroll
                for (int j = 0; j < TN; ++j)
                    acc[i][j] = fmaf(a[i], bb[j], acc[i][j]);
        }
        __syncthreads();
    }

#pragma unroll
    for (int i = 0; i < TM; ++i) {
        int m = m0 + rm*TM + i;
#pragma unroll
        for (int j = 0; j < TN; ++j) {
            int n = n0 + rn*TN + j;
            float v = acc[i][j];
            if constexpr (EPI == 2) { v = tanhf(v); }
            else if constexpr (EPI == 3) { v = expf(-expf(v + bias[n])); }
            Cd[(size_t)m*ldc + n] = v;
        }
    }
}

// ---------------------------------------------------------------------------
// Prep: dxprev = shifted(x) - x (f32); xin = x + dxprev*maa_x as bf16.
// ---------------------------------------------------------------------------
__global__ __launch_bounds__(256)
void prep_kernel(const float* __restrict__ x, const float* __restrict__ shift,
                 const float* __restrict__ maa_x,
                 float* __restrict__ dxprev, __hip_bfloat16* __restrict__ xin)
{
    size_t idx = (size_t)blockIdx.x*256 + threadIdx.x;
    int c = (int)(idx % CC);
    size_t bt = idx / CC;
    int t = (int)(bt % TT);
    int b = (int)(bt / TT);
    float xv = x[idx];
    float prev = t ? x[idx - CC] : shift[(size_t)b*CC + c];
    float dx = prev - xv;
    dxprev[idx] = dx;
    xin[idx] = __float2bfloat16(fmaf(dx, maa_x[c], xv));
}

// ---------------------------------------------------------------------------
// Fused: mix_f = xxx[:,f,:] @ maa_w2[f] (K=32 each, xxx ld=192), then
// xf = x + dx*(maa_f + mix_f). xw f32 (in-place over dx), others bf16.
// ---------------------------------------------------------------------------
__global__ __launch_bounds__(256)
void fusedmix_kernel(const float* __restrict__ xxx, const float* __restrict__ w2,
                     const float* __restrict__ x, const float* dx,
                     const float* __restrict__ maa_w, const float* __restrict__ maa_k,
                     const float* __restrict__ maa_v, const float* __restrict__ maa_r,
                     const float* __restrict__ maa_g,
                     float* xw, __hip_bfloat16* __restrict__ xk,
                     __hip_bfloat16* __restrict__ xv2, __hip_bfloat16* __restrict__ xr,
                     __hip_bfloat16* __restrict__ xg)
{
    __shared__ float w2s[160][64];
    const int c0 = blockIdx.x * 64, bt0 = blockIdx.y * 128;
    const int tid = threadIdx.x;
    const int tc = tid & 63, tb = tid >> 6;
    for (int idx = tid; idx < 160*64; idx += 256) {
        int kk = idx >> 6, cc = idx & 63;
        w2s[kk][cc] = w2[(size_t)kk*CC + c0 + cc];
    }
    __syncthreads();
    const int c = c0 + tc;
    const float mw_c = maa_w[c], mk_c = maa_k[c], mv_c = maa_v[c];
    const float mr_c = maa_r[c], mg_c = maa_g[c];
    for (int it = 0; it < 32; ++it) {
        int bt = bt0 + it*4 + tb;
        const float* xrow = xxx + (size_t)bt*192;
        float a0=0,a1=0,a2=0,a3=0,a4=0;
#pragma unroll
        for (int d2 = 0; d2 < 32; ++d2) {
            a0 = fmaf(xrow[d2],       w2s[d2][tc],       a0);
            a1 = fmaf(xrow[32+d2],    w2s[32+d2][tc],    a1);
            a2 = fmaf(xrow[64+d2],    w2s[64+d2][tc],    a2);
            a3 = fmaf(xrow[96+d2],    w2s[96+d2][tc],    a3);
            a4 = fmaf(xrow[128+d2],   w2s[128+d2][tc],   a4);
        }
        size_t idx = (size_t)bt*CC + c;
        float xval = x[idx], dv = dx[idx];
        xw[idx]  = fmaf(dv, mw_c + a0, xval);
        xk[idx]  = __float2bfloat16(fmaf(dv, mk_c + a1, xval));
        xv2[idx] = __float2bfloat16(fmaf(dv, mv_c + a2, xval));
        xr[idx]  = __float2bfloat16(fmaf(dv, mr_c + a3, xval));
        xg[idx]  = __float2bfloat16(fmaf(dv, mg_c + a4, xval));
    }
}

// ---------------------------------------------------------------------------
// WKV6 scan. Grid = B*H*4; ONE wave per block; wave owns 16 columns
// j = q*16 + (lane&15) of head (b,h); lane covers rows i0..i0+15.
// LDS double-buffered, padded (slot = i + i/16) -> conflict-free b128 reads.
// Global prefetch distance 3 via named register pairs (no runtime indexing).
// ---------------------------------------------------------------------------
__global__ __launch_bounds__(64)
void wkv_kernel(const float* __restrict__ r, const float* __restrict__ k,
                const float* __restrict__ v, const float* __restrict__ d,
                const float* __restrict__ u, const float* __restrict__ s0,
                float* __restrict__ y)
{
    const int bh = blockIdx.x >> 2, q = blockIdx.x & 3;
    const int b = bh >> 5, h = bh & 31;
    const int lane = threadIdx.x;
    const int gi = lane >> 4;
    const int i0 = gi * 16;
    const int jj = lane & 15;
    const int j  = q*16 + jj;
    const int slot = lane + gi;            // 17*gi + jj

    __shared__ float4 rkdw[2][68];

    float s[16];
    const float* sp = s0 + (size_t)bh*NN*NN;
#pragma unroll
    for (int ii = 0; ii < 16; ++ii) s[ii] = sp[(size_t)(i0+ii)*NN + j];

    const float ul = u[h*NN + lane];
    const size_t base = (size_t)b*TT*CC + (size_t)h*NN;

    // prologue: t=0 -> buf0; t=1 -> regs0; t=2 -> regs1
    float vj;
    {
        float rr = r[base + lane], kk = k[base + lane], dd = d[base + lane];
        vj = v[base + j];
        rkdw[0][slot] = make_float4(rr, kk, dd, rr*ul*kk);
    }
    float pr0 = r[base + CC + lane],   pk0 = k[base + CC + lane];
    float pd0 = d[base + CC + lane],   pv0 = v[base + CC + j];
    float pr1 = r[base + 2*CC + lane], pk1 = k[base + 2*CC + lane];
    float pd1 = d[base + 2*CC + lane], pv1 = v[base + 2*CC + j];

#define WKV_STEP(T_, CUR, PR, PK, PD, PV)                                     \
    {                                                                          \
        size_t off = base + (size_t)(T_)*CC;                                   \
        if ((T_) + 1 < TT)                                                     \
            rkdw[(CUR)^1][slot] = make_float4(PR, PK, PD, PR*ul*PK);           \
        float vn = PV;                                                         \
        if ((T_) + 3 < TT) {                                                   \
            size_t o3 = off + 3*CC;                                            \
            PR = r[o3 + lane]; PK = k[o3 + lane];                              \
            PD = d[o3 + lane]; PV = v[o3 + j];                                 \
        }                                                                      \
        float yp = 0.f, sv = 0.f;                                              \
        _Pragma("unroll")                                                      \
        for (int ii = 0; ii < 16; ++ii) {                                      \
            float4 qv = rkdw[CUR][gi*17 + ii];                                 \
            yp = fmaf(qv.x, s[ii], yp);                                        \
            sv += qv.w;                                                        \
            s[ii] = fmaf(qv.z, s[ii], qv.y * vj);                              \
        }                                                                      \
        float yj = fmaf(sv, vj, yp);                                           \
        yj += __shfl_xor(yj, 16);                                              \
        yj += __shfl_xor(yj, 32);                                              \
        if (lane < 16) y[off + q*16 + lane] = yj;                              \
        vj = vn;                                                               \
    }

    for (int t = 0; t < TT; t += 2) {
        WKV_STEP(t,     0, pr0, pk0, pd0, pv0);
        WKV_STEP(t + 1, 1, pr1, pk1, pd1, pv1);
    }
#undef WKV_STEP
}

// ---------------------------------------------------------------------------
// GroupNorm over N=64 per (b,t,h) + affine + gate; emits bf16 for Wo GEMM.
// ---------------------------------------------------------------------------
__global__ __launch_bounds__(256)
void gnorm_kernel(const float* __restrict__ y, const float* __restrict__ g,
                  const float* __restrict__ ln_g, const float* __restrict__ ln_b,
                  __hip_bfloat16* __restrict__ yg)
{
    int gidx = blockIdx.x*4 + (threadIdx.x >> 6);
    int lane = threadIdx.x & 63;
    int h = gidx % HH;
    int bt = gidx / HH;
    size_t idx = (size_t)bt*CC + (size_t)h*NN + lane;

    float val = y[idx];
    float sum = val, sq = val*val;
#pragma unroll
    for (int m = 1; m < 64; m <<= 1) {
        sum += __shfl_xor(sum, m, 64);
        sq  += __shfl_xor(sq,  m, 64);
    }
    float mean = sum * (1.f/64.f);
    float var  = sq  * (1.f/64.f) - mean*mean;
    float nv = (val - mean) * rsqrtf(var + EPSV);
    int c = h*NN + lane;
    yg[idx] = __float2bfloat16((nv * ln_g[c] + ln_b[c]) * g[idx]);
}

__global__ __launch_bounds__(256)
void shiftout_kernel(const float* __restrict__ x, float* __restrict__ o)
{
    int i = blockIdx.x*256 + threadIdx.x;  // B*C = 8192
    int b = i / CC, c = i % CC;
    o[i] = x[((size_t)b*TT + (TT-1))*CC + c];
}

// ---------------------------------------------------------------------------
extern "C" void kernel_launch(void* const* d_in, const int* in_sizes, int n_in,
                              void* d_out, int out_size, void* d_ws, size_t ws_size,
                              hipStream_t stream)
{
    const float* x          = (const float*)d_in[0];
    const float* shift_st   = (const float*)d_in[1];
    const float* wkv_state  = (const float*)d_in[2];
    const float* maa_x      = (const float*)d_in[3];
    const float* maa_w      = (const float*)d_in[4];
    const float* maa_k      = (const float*)d_in[5];
    const float* maa_v      = (const float*)d_in[6];
    const float* maa_r      = (const float*)d_in[7];
    const float* maa_g      = (const float*)d_in[8];
    const float* maa_w1     = (const float*)d_in[9];
    const float* maa_w2     = (const float*)d_in[10];
    const float* time_decay = (const float*)d_in[11];
    const float* decay_w1   = (const float*)d_in[12];
    const float* decay_w2   = (const float*)d_in[13];
    const float* time_faaaa = (const float*)d_in[14];
    const float* Wr         = (const float*)d_in[15];
    const float* Wk         = (const float*)d_in[16];
    const float* Wv         = (const float*)d_in[17];
    const float* Wg         = (const float*)d_in[18];
    const float* Wo         = (const float*)d_in[19];
    const float* ln_g       = (const float*)d_in[20];
    const float* ln_b       = (const float*)d_in[21];

    // f32 slots (16.78 MB each):
    //   fA: dxprev -> xw -> y      fB: decay
    //   fC: r   fD: k   fE: v   fF: g
    float* ws = (float*)d_ws;
    const size_t SL = (size_t)BT*CC;
    float* fA = ws;
    float* fB = fA + SL;
    float* fC = fB + SL;
    float* fD = fC + SL;
    float* fE = fD + SL;
    float* fF = fE + SL;
    float* xxx  = fF + SL;                    // 2048 x 192 f32 (padded)
    float* wtmp = xxx + (size_t)BT*192;       // 2048 x 64 f32
    // bf16 region
    __hip_bfloat16* hbase = (__hip_bfloat16*)(wtmp + (size_t)BT*DDEC);
    const size_t HL = (size_t)CC*CC;
    __hip_bfloat16* WrT  = hbase;
    __hip_bfloat16* WkT  = WrT + HL;
    __hip_bfloat16* WvT  = WkT + HL;
    __hip_bfloat16* WgT  = WvT + HL;
    __hip_bfloat16* WoT  = WgT + HL;
    __hip_bfloat16* bxr  = WoT + HL;
    __hip_bfloat16* bxk  = bxr + HL;
    __hip_bfloat16* bxv  = bxk + HL;
    __hip_bfloat16* bxg  = bxv + HL;
    __hip_bfloat16* byg  = bxg + HL;
    __hip_bfloat16* bxin = byg + HL;
    __hip_bfloat16* W1Tp = bxin + HL;         // 192 x 2048 bf16 (zero-padded)

    float* out       = (float*)d_out;
    float* out_shift = out + SL;
    float* out_state = out_shift + (size_t)BB*CC;

    const int EW_GRID = (int)(SL/256);
    dim3 tg(CC/64, CC/64);

    // 0) weight transposes
    transpose_cast<<<tg, 256, 0, stream>>>(Wr, WrT, CC, CC);
    transpose_cast<<<tg, 256, 0, stream>>>(Wk, WkT, CC, CC);
    transpose_cast<<<tg, 256, 0, stream>>>(Wv, WvT, CC, CC);
    transpose_cast<<<tg, 256, 0, stream>>>(Wg, WgT, CC, CC);
    transpose_cast<<<tg, 256, 0, stream>>>(Wo, WoT, CC, CC);
    transpose_cast_pad<<<dim3(3, CC/64), 256, 0, stream>>>(maa_w1, W1Tp, CC, 160);

    // 1) prep + trivial outputs
    prep_kernel<<<EW_GRID, 256, 0, stream>>>(x, shift_st, maa_x, fA, bxin);
    shiftout_kernel<<<BB*CC/256, 256, 0, stream>>>(x, out_shift);
    hipMemcpyAsync(out_state, wkv_state, (size_t)BB*HH*NN*NN*sizeof(float),
                   hipMemcpyDeviceToDevice, stream);

    // 2) xxx = tanh(xin @ maa_w1)  (2048 x 192pad, K=2048) via MFMA
    mm_bf16<64,2><<<dim3(3, BT/128), 256, 0, stream>>>(bxin, W1Tp, xxx, CC, 192);

    // 3) fused mix (xw f32 into fA in-place; xk/xv/xr/xg bf16)
    fusedmix_kernel<<<dim3(CC/64, BT/128), 256, 0, stream>>>(xxx, maa_w2, x, fA,
        maa_w, maa_k, maa_v, maa_r, maa_g, fA, bxk, bxv, bxr, bxg);

    // 4) wtmp = tanh(xw @ decay_w1) (2048 x 64, K=2048) f32
    sgemm<32,32,16,2,2,2><<<dim3(DDEC/32, BT/32), 256, 0, stream>>>(fA, decay_w1,
        wtmp, BT, DDEC, CC, CC, DDEC, DDEC, nullptr);

    // 5) decay = exp(-exp(wtmp @ decay_w2 + time_decay))  (K=64) -> fB
    sgemm<128,128,16,8,8,3><<<dim3(CC/128, BT/128), 256, 0, stream>>>(wtmp,
        decay_w2, fB, BT, CC, DDEC, DDEC, CC, CC, time_decay);

    // 6) r/k/v/g GEMMs, z-batched (1024 blocks -> ~4 blocks/CU)
    mm_bf16_b4<<<dim3(CC/128, BT/128, 4), 256, 0, stream>>>(
        bxr, bxk, bxv, bxg, WrT, WkT, WvT, WgT, fC, fD, fE, fF, CC);

    // 7) WKV scan: y -> fA
    wkv_kernel<<<BB*HH*4, 64, 0, stream>>>(fC, fD, fE, fB, time_faaaa,
                                           wkv_state, fA);

    // 8) groupnorm + gate -> bf16 yg
    gnorm_kernel<<<BB*TT*HH/4, 256, 0, stream>>>(fA, fF, ln_g, ln_b, byg);

    // 9) out = yg @ Wo (128x64 tile -> 512 blocks)
    mm_bf16<64,0><<<dim3(CC/64, BT/128), 256, 0, stream>>>(byg, WoT, out, CC, CC);
}

// Round 4
// 692.358 us; speedup vs baseline: 3.2560x; 1.1794x over previous
//
#include <hip/hip_runtime.h>
#include <hip/hip_bf16.h>
#include <cstdint>
#include <cstddef>

// Problem constants (B,T,C,H) = (4,512,2048,32), N=64
#define BB 4
#define TT 512
#define CC 2048
#define HH 32
#define NN 64
#define BT (BB*TT)     // 2048 rows for all GEMMs
#define DMIX 32
#define DDEC 64
#define CH 64          // wkv chunk length
#define NCH (TT/CH)    // 8 chunks
static constexpr float EPSV = 1e-5f * 64.0f;  // 1e-5 * 8^2

typedef __attribute__((ext_vector_type(8))) short bf16x8;
typedef __attribute__((ext_vector_type(4))) float f32x4;

// ---------------------------------------------------------------------------
// async global->LDS, 16B per lane: lane i lands at lds_base + i*16.
// ---------------------------------------------------------------------------
__device__ __forceinline__ void gload16(const void* g, void* l) {
    __builtin_amdgcn_global_load_lds(
        (const __attribute__((address_space(1))) unsigned int*)g,
        (__attribute__((address_space(3))) unsigned int*)l, 16, 0, 0);
}

// ---------------------------------------------------------------------------
// bf16 MFMA GEMM core. 128 x BN tile, BK=32, 4 waves (2x2), wave = 64 x BN/2.
// A: MxK row-major bf16 (lda=K). Bt: NxK row-major bf16 (pre-transposed).
// C: f32 row-major (ldc). epi: 0=none, 1=silu, 2=tanh.
// ---------------------------------------------------------------------------
template<int BN>
__device__ __forceinline__
void mm_core(const __hip_bfloat16* __restrict__ A, const __hip_bfloat16* __restrict__ Bt,
             float* __restrict__ C, int K, int ldc, int epi, int bx, int by)
{
    constexpr int NF = BN/32;                 // frags per wave in N
    __shared__ __hip_bfloat16 As[128][32];
    __shared__ __hip_bfloat16 Bs[BN][32];
    const int tid = threadIdx.x, wid = tid >> 6, lane = tid & 63;
    const int m0 = by * 128, n0 = bx * BN;
    const int wr = wid >> 1, wc = wid & 1;

    f32x4 acc[4][NF] = {};

    const int srow = wid*16 + (lane >> 2);
    const int scol = (lane & 3) * 8;
    const __hip_bfloat16* aSrc = A  + (size_t)(m0 + srow)*K + scol;
    const __hip_bfloat16* bSrc = Bt + (size_t)(n0 + srow)*K + scol;
    __hip_bfloat16* aDst0 = &As[wid*16][0];
    __hip_bfloat16* aDst1 = &As[64 + wid*16][0];
    __hip_bfloat16* bDst0 = &Bs[wid*16][0];

    const int fr = lane & 15;
    const int kg = (lane >> 4) * 8;

    for (int k0 = 0; k0 < K; k0 += 32) {
        gload16(aSrc + k0,                aDst0);
        gload16(aSrc + (size_t)64*K + k0, aDst1);
        gload16(bSrc + k0,                bDst0);
        if constexpr (BN == 128)
            gload16(bSrc + (size_t)64*K + k0, &Bs[64 + wid*16][0]);
        __syncthreads();
        bf16x8 af[4], bf[NF];
#pragma unroll
        for (int m = 0; m < 4; ++m)
            af[m] = *(const bf16x8*)&As[wr*64 + m*16 + fr][kg];
#pragma unroll
        for (int n = 0; n < NF; ++n)
            bf[n] = *(const bf16x8*)&Bs[wc*(BN/2) + n*16 + fr][kg];
#pragma unroll
        for (int m = 0; m < 4; ++m)
#pragma unroll
            for (int n = 0; n < NF; ++n)
                acc[m][n] = __builtin_amdgcn_mfma_f32_16x16x32_bf16(
                                af[m], bf[n], acc[m][n], 0, 0, 0);
        __syncthreads();
    }

    // C/D layout: col = lane&15, row = (lane>>4)*4 + reg   [m89]
    const int rg = (lane >> 4) * 4;
#pragma unroll
    for (int m = 0; m < 4; ++m) {
#pragma unroll
        for (int n = 0; n < NF; ++n) {
#pragma unroll
            for (int rI = 0; rI < 4; ++rI) {
                int row = m0 + wr*64 + m*16 + rg + rI;
                int col = n0 + wc*(BN/2) + n*16 + fr;
                float v = acc[m][n][rI];
                if (epi == 1)      v = v / (1.f + expf(-v));
                else if (epi == 2) v = tanhf(v);
                C[(size_t)row*ldc + col] = v;
            }
        }
    }
}

template<int BN, int EPI>
__global__ __launch_bounds__(256)
void mm_bf16(const __hip_bfloat16* __restrict__ A, const __hip_bfloat16* __restrict__ Bt,
             float* __restrict__ C, int K, int ldc)
{
    mm_core<BN>(A, Bt, C, K, ldc, EPI, blockIdx.x, blockIdx.y);
}

// z-batched: 4 independent GEMMs (r,k,v,g), z==3 applies silu.
__global__ __launch_bounds__(256)
void mm_bf16_b4(const __hip_bfloat16* A0, const __hip_bfloat16* A1,
                const __hip_bfloat16* A2, const __hip_bfloat16* A3,
                const __hip_bfloat16* B0, const __hip_bfloat16* B1,
                const __hip_bfloat16* B2, const __hip_bfloat16* B3,
                float* C0, float* C1, float* C2, float* C3, int K)
{
    int z = blockIdx.z;
    const __hip_bfloat16* A = (z==0)?A0:(z==1)?A1:(z==2)?A2:A3;
    const __hip_bfloat16* B = (z==0)?B0:(z==1)?B1:(z==2)?B2:B3;
    float* C = (z==0)?C0:(z==1)?C1:(z==2)?C2:C3;
    mm_core<128>(A, B, C, K, CC, (z==3)?1:0, blockIdx.x, blockIdx.y);
}

// ---------------------------------------------------------------------------
// Weight transpose + cast: W[K][N] f32 -> Wt[N][K] bf16. 64x64 tiles.
// ---------------------------------------------------------------------------
__global__ __launch_bounds__(256)
void transpose_cast(const float* __restrict__ W, __hip_bfloat16* __restrict__ Wt,
                    int K, int N)
{
    __shared__ float tile[64][65];
    const int kb = blockIdx.y * 64, nb = blockIdx.x * 64;
    const int tr = threadIdx.x >> 6, tc = threadIdx.x & 63;
#pragma unroll
    for (int p = 0; p < 16; ++p)
        tile[tr + p*4][tc] = W[(size_t)(kb + tr + p*4)*N + nb + tc];
    __syncthreads();
#pragma unroll
    for (int p = 0; p < 16; ++p)
        Wt[(size_t)(nb + tr + p*4)*K + kb + tc] =
            __float2bfloat16(tile[tc][tr + p*4]);
}

// Same but source has Nsrc cols; dest rows beyond Nsrc are zero (pad to grid).
__global__ __launch_bounds__(256)
void transpose_cast_pad(const float* __restrict__ W, __hip_bfloat16* __restrict__ Wt,
                        int K, int Nsrc)
{
    __shared__ float tile[64][65];
    const int kb = blockIdx.y * 64, nb = blockIdx.x * 64;
    const int tr = threadIdx.x >> 6, tc = threadIdx.x & 63;
#pragma unroll
    for (int p = 0; p < 16; ++p) {
        int col = nb + tc;
        tile[tr + p*4][tc] = (col < Nsrc) ?
            W[(size_t)(kb + tr + p*4)*Nsrc + col] : 0.f;
    }
    __syncthreads();
#pragma unroll
    for (int p = 0; p < 16; ++p)
        Wt[(size_t)(nb + tr + p*4)*K + kb + tc] =
            __float2bfloat16(tile[tc][tr + p*4]);
}

// ---------------------------------------------------------------------------
// Generic f32 SGEMM (skinny / decay path). EPI: 0=none, 2=tanh,
// 3=exp(-exp(v + bias[n]))
// ---------------------------------------------------------------------------
template<int BM,int BN,int BK,int TM,int TN,int EPI>
__global__ __launch_bounds__((BM/TM)*(BN/TN))
void sgemm(const float* __restrict__ A, const float* __restrict__ B,
           float* __restrict__ Cd, int M, int N, int K,
           int lda, int ldb, int ldc, const float* __restrict__ bias)
{
    constexpr int NT = (BM/TM)*(BN/TN);
    __shared__ float As[BK][BM + 4];
    __shared__ float Bs[BK][BN];
    const int tid = threadIdx.x;
    const int m0 = blockIdx.y * BM;
    const int n0 = blockIdx.x * BN;
    const int rm = tid / (BN/TN);
    const int rn = tid % (BN/TN);

    float acc[TM][TN];
#pragma unroll
    for (int i = 0; i < TM; ++i)
#pragma unroll
        for (int j = 0; j < TN; ++j) acc[i][j] = 0.f;

    for (int k0 = 0; k0 < K; k0 += BK) {
#pragma unroll
        for (int p = 0; p < (BM*BK)/NT; ++p) {
            int i  = tid + p*NT;
            int m  = i / BK, kk = i % BK;
            As[kk][m] = A[(size_t)(m0+m)*lda + (k0+kk)];
        }
#pragma unroll
        for (int p = 0; p < (BK*BN)/NT; ++p) {
            int i  = tid + p*NT;
            int kk = i / BN, n = i % BN;
            Bs[kk][n] = B[(size_t)(k0+kk)*ldb + (n0+n)];
        }
        __syncthreads();
#pragma unroll
        for (int kk = 0; kk < BK; ++kk) {
            float a[TM], bb[TN];
#pragma unroll
            for (int i = 0; i < TM; ++i) a[i] = As[kk][rm*TM+i];
#pragma unroll
            for (int j = 0; j < TN; ++j) bb[j] = Bs[kk][rn*TN+j];
#pragma unroll
            for (int i = 0; i < TM; ++i)
#pragma unroll
                for (int j = 0; j < TN; ++j)
                    acc[i][j] = fmaf(a[i], bb[j], acc[i][j]);
        }
        __syncthreads();
    }

#pragma unroll
    for (int i = 0; i < TM; ++i) {
        int m = m0 + rm*TM + i;
#pragma unroll
        for (int j = 0; j < TN; ++j) {
            int n = n0 + rn*TN + j;
            float v = acc[i][j];
            if constexpr (EPI == 2) { v = tanhf(v); }
            else if constexpr (EPI == 3) { v = expf(-expf(v + bias[n])); }
            Cd[(size_t)m*ldc + n] = v;
        }
    }
}

// ---------------------------------------------------------------------------
// Prep: dxprev = shifted(x) - x (f32); xin = x + dxprev*maa_x as bf16.
// ---------------------------------------------------------------------------
__global__ __launch_bounds__(256)
void prep_kernel(const float* __restrict__ x, const float* __restrict__ shift,
                 const float* __restrict__ maa_x,
                 float* __restrict__ dxprev, __hip_bfloat16* __restrict__ xin)
{
    size_t idx = (size_t)blockIdx.x*256 + threadIdx.x;
    int c = (int)(idx % CC);
    size_t bt = idx / CC;
    int t = (int)(bt % TT);
    int b = (int)(bt / TT);
    float xv = x[idx];
    float prev = t ? x[idx - CC] : shift[(size_t)b*CC + c];
    float dx = prev - xv;
    dxprev[idx] = dx;
    xin[idx] = __float2bfloat16(fmaf(dx, maa_x[c], xv));
}

// ---------------------------------------------------------------------------
// Fused: mix_f = xxx[:,f,:] @ maa_w2[f] (K=32 each, xxx ld=192), then
// xf = x + dx*(maa_f + mix_f). xw f32 (in-place over dx), others bf16.
// ---------------------------------------------------------------------------
__global__ __launch_bounds__(256)
void fusedmix_kernel(const float* __restrict__ xxx, const float* __restrict__ w2,
                     const float* __restrict__ x, const float* dx,
                     const float* __restrict__ maa_w, const float* __restrict__ maa_k,
                     const float* __restrict__ maa_v, const float* __restrict__ maa_r,
                     const float* __restrict__ maa_g,
                     float* xw, __hip_bfloat16* __restrict__ xk,
                     __hip_bfloat16* __restrict__ xv2, __hip_bfloat16* __restrict__ xr,
                     __hip_bfloat16* __restrict__ xg)
{
    __shared__ float w2s[160][64];
    const int c0 = blockIdx.x * 64, bt0 = blockIdx.y * 128;
    const int tid = threadIdx.x;
    const int tc = tid & 63, tb = tid >> 6;
    for (int idx = tid; idx < 160*64; idx += 256) {
        int kk = idx >> 6, cc = idx & 63;
        w2s[kk][cc] = w2[(size_t)kk*CC + c0 + cc];
    }
    __syncthreads();
    const int c = c0 + tc;
    const float mw_c = maa_w[c], mk_c = maa_k[c], mv_c = maa_v[c];
    const float mr_c = maa_r[c], mg_c = maa_g[c];
    for (int it = 0; it < 32; ++it) {
        int bt = bt0 + it*4 + tb;
        const float* xrow = xxx + (size_t)bt*192;
        float a0=0,a1=0,a2=0,a3=0,a4=0;
#pragma unroll
        for (int d2 = 0; d2 < 32; ++d2) {
            a0 = fmaf(xrow[d2],       w2s[d2][tc],       a0);
            a1 = fmaf(xrow[32+d2],    w2s[32+d2][tc],    a1);
            a2 = fmaf(xrow[64+d2],    w2s[64+d2][tc],    a2);
            a3 = fmaf(xrow[96+d2],    w2s[96+d2][tc],    a3);
            a4 = fmaf(xrow[128+d2],   w2s[128+d2][tc],   a4);
        }
        size_t idx = (size_t)bt*CC + c;
        float xval = x[idx], dv = dx[idx];
        xw[idx]  = fmaf(dv, mw_c + a0, xval);
        xk[idx]  = __float2bfloat16(fmaf(dv, mk_c + a1, xval));
        xv2[idx] = __float2bfloat16(fmaf(dv, mv_c + a2, xval));
        xr[idx]  = __float2bfloat16(fmaf(dv, mr_c + a3, xval));
        xg[idx]  = __float2bfloat16(fmaf(dv, mg_c + a4, xval));
    }
}

// ---------------------------------------------------------------------------
// WKV6 chunked parallel scan. Chunk length CH=64, NCH=8 chunks.
// Recurrence: S_{t+1} = d_t (.) S_t + k_t v_t^T ; y_t = r_t @ (S_t + u(.)k_t v_t^T)
//
// K1 (summary, grid B*H*NCH): Bc[i][j] = sum_t (prod_{t<s<L} d_s[i]) k_t[i] v_t[j]
//   (suffix-product form, no division), cpf[i] = prod of all d in chunk.
// K2 (boundary scan, grid B*H): S_{c+1} = cpf_c (.) S_c + Bc; stores S_c.
// K3 (output, grid B*H*NCH): Y = masked(Q~ K~^T, diag=u-term) @ V + Q~ @ S_c
//   with Q~_t = r_t (.) cpe_t, K~_t = k_t / cpe_{t+1} (cpe = exclusive cumprod).
// ---------------------------------------------------------------------------
__global__ __launch_bounds__(256)
void wkv_chunk_summary(const float* __restrict__ k, const float* __restrict__ v,
                       const float* __restrict__ d,
                       float* __restrict__ Bc, float* __restrict__ cpf)
{
    __shared__ float khat[64][64];
    __shared__ float vs[64][64];
    const int task = blockIdx.x;
    const int bh = task >> 3, c = task & 7;
    const int b = bh >> 5, h = bh & 31;
    const int tid = threadIdx.x;
    const size_t base = ((size_t)b*TT + c*CH)*CC + h*NN;

    if (tid < 64) {
        const int i = tid;
        const float* kg = k + base + i;
        const float* dg = d + base + i;
        float sp = 1.f;
#pragma unroll 8
        for (int t = 63; t >= 0; --t) {
            float kv = kg[(size_t)t*CC];
            float dv = dg[(size_t)t*CC];
            khat[t][i] = kv * sp;          // k_t * prod_{t<s<L} d_s
            sp *= dv;
        }
        cpf[(size_t)task*64 + i] = sp;
    } else if (tid < 192) {
        const int lin = tid - 64;          // 128 threads load 1024 float4
#pragma unroll
        for (int p = 0; p < 8; ++p) {
            int f4 = lin + p*128;
            int t = f4 >> 4, j4 = (f4 & 15)*4;
            *(float4*)&vs[t][j4] = *(const float4*)(v + base + (size_t)t*CC + j4);
        }
    }
    __syncthreads();

    const int i0 = (tid >> 4)*4, j0 = (tid & 15)*4;
    float acc[4][4] = {};
#pragma unroll 4
    for (int t = 0; t < 64; ++t) {
        float4 m = *(const float4*)&khat[t][i0];
        float4 n = *(const float4*)&vs[t][j0];
        acc[0][0] = fmaf(m.x,n.x,acc[0][0]); acc[0][1] = fmaf(m.x,n.y,acc[0][1]);
        acc[0][2] = fmaf(m.x,n.z,acc[0][2]); acc[0][3] = fmaf(m.x,n.w,acc[0][3]);
        acc[1][0] = fmaf(m.y,n.x,acc[1][0]); acc[1][1] = fmaf(m.y,n.y,acc[1][1]);
        acc[1][2] = fmaf(m.y,n.z,acc[1][2]); acc[1][3] = fmaf(m.y,n.w,acc[1][3]);
        acc[2][0] = fmaf(m.z,n.x,acc[2][0]); acc[2][1] = fmaf(m.z,n.y,acc[2][1]);
        acc[2][2] = fmaf(m.z,n.z,acc[2][2]); acc[2][3] = fmaf(m.z,n.w,acc[2][3]);
        acc[3][0] = fmaf(m.w,n.x,acc[3][0]); acc[3][1] = fmaf(m.w,n.y,acc[3][1]);
        acc[3][2] = fmaf(m.w,n.z,acc[3][2]); acc[3][3] = fmaf(m.w,n.w,acc[3][3]);
    }
    float* Bg = Bc + (size_t)task*4096;
#pragma unroll
    for (int a4 = 0; a4 < 4; ++a4)
        *(float4*)&Bg[(i0+a4)*64 + j0] =
            make_float4(acc[a4][0], acc[a4][1], acc[a4][2], acc[a4][3]);
}

__global__ __launch_bounds__(256)
void wkv_chunk_scan(const float* __restrict__ s0, const float* __restrict__ Bc,
                    const float* __restrict__ cpf, float* __restrict__ Sc)
{
    const int bh = blockIdx.x, tid = threadIdx.x;
    float S[16];
    const float* sp = s0 + (size_t)bh*4096;
#pragma unroll
    for (int p = 0; p < 16; ++p) S[p] = sp[p*256 + tid];
    for (int c = 0; c < NCH; ++c) {
        const size_t tk = (size_t)bh*NCH + c;
        const float* B  = Bc  + tk*4096;
        const float* cp = cpf + tk*64;
        float* so = Sc + tk*4096;
#pragma unroll
        for (int p = 0; p < 16; ++p) {
            int e = p*256 + tid;
            so[e] = S[p];
            S[p] = fmaf(cp[e >> 6], S[p], B[e]);
        }
    }
}

__global__ __launch_bounds__(256)
void wkv_chunk_out(const float* __restrict__ r, const float* __restrict__ k,
                   const float* __restrict__ v, const float* __restrict__ d,
                   const float* __restrict__ u, const float* __restrict__ Sc,
                   float* __restrict__ y)
{
    __shared__ float qsT[64][68];     // q~^T : [i][t]
    __shared__ float ktsT[64][68];    // k~^T : [i][t], later AT[t'][t]
    __shared__ float vs[64][64];
    __shared__ float Ss[64][64];
    __shared__ float diag[64];
    const int task = blockIdx.x;
    const int bh = task >> 3, c = task & 7;
    const int b = bh >> 5, h = bh & 31;
    const int tid = threadIdx.x;
    const size_t base = ((size_t)b*TT + c*CH)*CC + h*NN;

    if (tid < 64) {
        const int i = tid;
        const float* rg = r + base + i;
        const float* kg = k + base + i;
        const float* dg = d + base + i;
        float p = 1.f;
#pragma unroll 8
        for (int t = 0; t < 64; ++t) {
            float rv = rg[(size_t)t*CC];
            float kv = kg[(size_t)t*CC];
            float dv = dg[(size_t)t*CC];
            qsT[i][t] = rv * p;           // r (.) cpe_t
            float pd = p * dv;            // cpe_{t+1}
            ktsT[i][t] = kv / pd;         // k / cpe_{t+1}
            p = pd;
        }
    } else if (tid < 128) {
        const int t = tid - 64;
        const float* rrow = r + base + (size_t)t*CC;
        const float* krow = k + base + (size_t)t*CC;
        const float* urow = u + h*NN;
        float acc = 0.f;
#pragma unroll
        for (int q4 = 0; q4 < 16; ++q4) {
            float4 rq = *(const float4*)(rrow + q4*4);
            float4 kq = *(const float4*)(krow + q4*4);
            float4 uq = *(const float4*)(urow + q4*4);
            acc += rq.x*uq.x*kq.x + rq.y*uq.y*kq.y + rq.z*uq.z*kq.z + rq.w*uq.w*kq.w;
        }
        diag[t] = acc;
    } else if (tid < 192) {
        const int lin = tid - 128;
#pragma unroll
        for (int p4 = 0; p4 < 16; ++p4) {
            int f4 = lin + p4*64;
            int t = f4 >> 4, j4 = (f4 & 15)*4;
            *(float4*)&vs[t][j4] = *(const float4*)(v + base + (size_t)t*CC + j4);
        }
    } else {
        const int lin = tid - 192;
        const float* sg = Sc + (size_t)task*4096;
#pragma unroll
        for (int p4 = 0; p4 < 16; ++p4) {
            int f4 = lin + p4*64;
            *(float4*)&Ss[f4 >> 4][(f4 & 15)*4] = *(const float4*)(sg + f4*4);
        }
    }
    __syncthreads();

    // A-stage: AT[t'][t] = sum_i k~[t'][i] * q~[t][i]
    const int t0  = (tid & 15)*4;      // t (col)
    const int tp0 = (tid >> 4)*4;      // t' (row)
    float a[4][4] = {};
#pragma unroll 4
    for (int i = 0; i < 64; ++i) {
        float4 m = *(const float4*)&ktsT[i][tp0];
        float4 n = *(const float4*)&qsT[i][t0];
        a[0][0] = fmaf(m.x,n.x,a[0][0]); a[0][1] = fmaf(m.x,n.y,a[0][1]);
        a[0][2] = fmaf(m.x,n.z,a[0][2]); a[0][3] = fmaf(m.x,n.w,a[0][3]);
        a[1][0] = fmaf(m.y,n.x,a[1][0]); a[1][1] = fmaf(m.y,n.y,a[1][1]);
        a[1][2] = fmaf(m.y,n.z,a[1][2]); a[1][3] = fmaf(m.y,n.w,a[1][3]);
        a[2][0] = fmaf(m.z,n.x,a[2][0]); a[2][1] = fmaf(m.z,n.y,a[2][1]);
        a[2][2] = fmaf(m.z,n.z,a[2][2]); a[2][3] = fmaf(m.z,n.w,a[2][3]);
        a[3][0] = fmaf(m.w,n.x,a[3][0]); a[3][1] = fmaf(m.w,n.y,a[3][1]);
        a[3][2] = fmaf(m.w,n.z,a[3][2]); a[3][3] = fmaf(m.w,n.w,a[3][3]);
    }
    // mask: keep t'<t, diag at t'==t, zero above
    float am[4][4];
#pragma unroll
    for (int a4 = 0; a4 < 4; ++a4)
#pragma unroll
        for (int b4 = 0; b4 < 4; ++b4) {
            int tp = tp0 + a4, t = t0 + b4;
            am[a4][b4] = (tp < t) ? a[a4][b4] : (tp == t ? diag[t] : 0.f);
        }
    __syncthreads();                   // all reads of ktsT done
#pragma unroll
    for (int a4 = 0; a4 < 4; ++a4)
#pragma unroll
        for (int b4 = 0; b4 < 4; ++b4)
            ktsT[tp0 + a4][t0 + b4] = am[a4][b4];   // ktsT now holds AT
    __syncthreads();

    // Y-stage: Y[t][j] = sum_{t'} AT[t'][t] vs[t'][j] + sum_i qsT[i][t] Ss[i][j]
    const int j0 = (tid & 15)*4;
    const int y0 = (tid >> 4)*4;
    float acc[4][4] = {};
#pragma unroll 4
    for (int kk = 0; kk < 64; ++kk) {
        float4 m = *(const float4*)&ktsT[kk][y0];
        float4 n = *(const float4*)&vs[kk][j0];
        acc[0][0] = fmaf(m.x,n.x,acc[0][0]); acc[0][1] = fmaf(m.x,n.y,acc[0][1]);
        acc[0][2] = fmaf(m.x,n.z,acc[0][2]); acc[0][3] = fmaf(m.x,n.w,acc[0][3]);
        acc[1][0] = fmaf(m.y,n.x,acc[1][0]); acc[1][1] = fmaf(m.y,n.y,acc[1][1]);
        acc[1][2] = fmaf(m.y,n.z,acc[1][2]); acc[1][3] = fmaf(m.y,n.w,acc[1][3]);
        acc[2][0] = fmaf(m.z,n.x,acc[2][0]); acc[2][1] = fmaf(m.z,n.y,acc[2][1]);
        acc[2][2] = fmaf(m.z,n.z,acc[2][2]); acc[2][3] = fmaf(m.z,n.w,acc[2][3]);
        acc[3][0] = fmaf(m.w,n.x,acc[3][0]); acc[3][1] = fmaf(m.w,n.y,acc[3][1]);
        acc[3][2] = fmaf(m.w,n.z,acc[3][2]); acc[3][3] = fmaf(m.w,n.w,acc[3][3]);
    }
#pragma unroll 4
    for (int kk = 0; kk < 64; ++kk) {
        float4 m = *(const float4*)&qsT[kk][y0];
        float4 n = *(const float4*)&Ss[kk][j0];
        acc[0][0] = fmaf(m.x,n.x,acc[0][0]); acc[0][1] = fmaf(m.x,n.y,acc[0][1]);
        acc[0][2] = fmaf(m.x,n.z,acc[0][2]); acc[0][3] = fmaf(m.x,n.w,acc[0][3]);
        acc[1][0] = fmaf(m.y,n.x,acc[1][0]); acc[1][1] = fmaf(m.y,n.y,acc[1][1]);
        acc[1][2] = fmaf(m.y,n.z,acc[1][2]); acc[1][3] = fmaf(m.y,n.w,acc[1][3]);
        acc[2][0] = fmaf(m.z,n.x,acc[2][0]); acc[2][1] = fmaf(m.z,n.y,acc[2][1]);
        acc[2][2] = fmaf(m.z,n.z,acc[2][2]); acc[2][3] = fmaf(m.z,n.w,acc[2][3]);
        acc[3][0] = fmaf(m.w,n.x,acc[3][0]); acc[3][1] = fmaf(m.w,n.y,acc[3][1]);
        acc[3][2] = fmaf(m.w,n.z,acc[3][2]); acc[3][3] = fmaf(m.w,n.w,acc[3][3]);
    }
#pragma unroll
    for (int a4 = 0; a4 < 4; ++a4)
        *(float4*)(y + base + (size_t)(y0 + a4)*CC + j0) =
            make_float4(acc[a4][0], acc[a4][1], acc[a4][2], acc[a4][3]);
}

// ---------------------------------------------------------------------------
// GroupNorm over N=64 per (b,t,h) + affine + gate; emits bf16 for Wo GEMM.
// ---------------------------------------------------------------------------
__global__ __launch_bounds__(256)
void gnorm_kernel(const float* __restrict__ y, const float* __restrict__ g,
                  const float* __restrict__ ln_g, const float* __restrict__ ln_b,
                  __hip_bfloat16* __restrict__ yg)
{
    int gidx = blockIdx.x*4 + (threadIdx.x >> 6);
    int lane = threadIdx.x & 63;
    int h = gidx % HH;
    int bt = gidx / HH;
    size_t idx = (size_t)bt*CC + (size_t)h*NN + lane;

    float val = y[idx];
    float sum = val, sq = val*val;
#pragma unroll
    for (int m = 1; m < 64; m <<= 1) {
        sum += __shfl_xor(sum, m, 64);
        sq  += __shfl_xor(sq,  m, 64);
    }
    float mean = sum * (1.f/64.f);
    float var  = sq  * (1.f/64.f) - mean*mean;
    float nv = (val - mean) * rsqrtf(var + EPSV);
    int c = h*NN + lane;
    yg[idx] = __float2bfloat16((nv * ln_g[c] + ln_b[c]) * g[idx]);
}

__global__ __launch_bounds__(256)
void shiftout_kernel(const float* __restrict__ x, float* __restrict__ o)
{
    int i = blockIdx.x*256 + threadIdx.x;  // B*C = 8192
    int b = i / CC, c = i % CC;
    o[i] = x[((size_t)b*TT + (TT-1))*CC + c];
}

// ---------------------------------------------------------------------------
extern "C" void kernel_launch(void* const* d_in, const int* in_sizes, int n_in,
                              void* d_out, int out_size, void* d_ws, size_t ws_size,
                              hipStream_t stream)
{
    const float* x          = (const float*)d_in[0];
    const float* shift_st   = (const float*)d_in[1];
    const float* wkv_state  = (const float*)d_in[2];
    const float* maa_x      = (const float*)d_in[3];
    const float* maa_w      = (const float*)d_in[4];
    const float* maa_k      = (const float*)d_in[5];
    const float* maa_v      = (const float*)d_in[6];
    const float* maa_r      = (const float*)d_in[7];
    const float* maa_g      = (const float*)d_in[8];
    const float* maa_w1     = (const float*)d_in[9];
    const float* maa_w2     = (const float*)d_in[10];
    const float* time_decay = (const float*)d_in[11];
    const float* decay_w1   = (const float*)d_in[12];
    const float* decay_w2   = (const float*)d_in[13];
    const float* time_faaaa = (const float*)d_in[14];
    const float* Wr         = (const float*)d_in[15];
    const float* Wk         = (const float*)d_in[16];
    const float* Wv         = (const float*)d_in[17];
    const float* Wg         = (const float*)d_in[18];
    const float* Wo         = (const float*)d_in[19];
    const float* ln_g       = (const float*)d_in[20];
    const float* ln_b       = (const float*)d_in[21];

    // f32 slots (16.78 MB each):
    //   fA: dxprev -> xw -> Bc -> y     fB: decay
    //   fC: r   fD: k   fE: v   fF: g
    float* ws = (float*)d_ws;
    const size_t SL = (size_t)BT*CC;
    float* fA = ws;
    float* fB = fA + SL;
    float* fC = fB + SL;
    float* fD = fC + SL;
    float* fE = fD + SL;
    float* fF = fE + SL;
    float* xxx  = fF + SL;                    // 2048 x 192 f32 (padded)
    float* wtmp = xxx + (size_t)BT*192;       // 2048 x 64 f32
    // bf16 region
    __hip_bfloat16* hbase = (__hip_bfloat16*)(wtmp + (size_t)BT*DDEC);
    const size_t HL = (size_t)CC*CC;
    __hip_bfloat16* WrT  = hbase;
    __hip_bfloat16* WkT  = WrT + HL;
    __hip_bfloat16* WvT  = WkT + HL;
    __hip_bfloat16* WgT  = WvT + HL;
    __hip_bfloat16* WoT  = WgT + HL;
    __hip_bfloat16* bxr  = WoT + HL;
    __hip_bfloat16* bxk  = bxr + HL;
    __hip_bfloat16* bxv  = bxk + HL;
    __hip_bfloat16* bxg  = bxv + HL;
    __hip_bfloat16* byg  = bxg + HL;
    __hip_bfloat16* bxin = byg + HL;
    __hip_bfloat16* W1Tp = bxin + HL;         // 192 x 2048 bf16 (zero-padded)

    // wkv chunk scratch (aliased onto dead regions):
    //   Bc  -> fA (xw dead after step 4; y written only in K3, after Bc consumed)
    //   Sc  -> byg region (byg written at step 8, after K3 consumed Sc)
    //   cpf -> tail of the byg..W1Tp span (past Sc's 16.78 MB)
    float* Bc  = fA;
    float* Sc  = (float*)byg;
    float* cpf = Sc + (size_t)BB*HH*NCH*NN*NN / 1;   // placed right after Sc
    // NOTE: Sc spans 16.78 MB of the byg(8.39)+bxin(8.39)+W1Tp(0.79) = 17.57 MB
    // span; cpf (262 KB) fits in the remaining tail.

    float* out       = (float*)d_out;
    float* out_shift = out + SL;
    float* out_state = out_shift + (size_t)BB*CC;

    const int EW_GRID = (int)(SL/256);
    dim3 tg(CC/64, CC/64);

    // 0) weight transposes
    transpose_cast<<<tg, 256, 0, stream>>>(Wr, WrT, CC, CC);
    transpose_cast<<<tg, 256, 0, stream>>>(Wk, WkT, CC, CC);
    transpose_cast<<<tg, 256, 0, stream>>>(Wv, WvT, CC, CC);
    transpose_cast<<<tg, 256, 0, stream>>>(Wg, WgT, CC, CC);
    transpose_cast<<<tg, 256, 0, stream>>>(Wo, WoT, CC, CC);
    transpose_cast_pad<<<dim3(3, CC/64), 256, 0, stream>>>(maa_w1, W1Tp, CC, 160);

    // 1) prep + trivial outputs
    prep_kernel<<<EW_GRID, 256, 0, stream>>>(x, shift_st, maa_x, fA, bxin);
    shiftout_kernel<<<BB*CC/256, 256, 0, stream>>>(x, out_shift);
    hipMemcpyAsync(out_state, wkv_state, (size_t)BB*HH*NN*NN*sizeof(float),
                   hipMemcpyDeviceToDevice, stream);

    // 2) xxx = tanh(xin @ maa_w1)  (2048 x 192pad, K=2048) via MFMA
    mm_bf16<64,2><<<dim3(3, BT/128), 256, 0, stream>>>(bxin, W1Tp, xxx, CC, 192);

    // 3) fused mix (xw f32 into fA in-place; xk/xv/xr/xg bf16)
    fusedmix_kernel<<<dim3(CC/64, BT/128), 256, 0, stream>>>(xxx, maa_w2, x, fA,
        maa_w, maa_k, maa_v, maa_r, maa_g, fA, bxk, bxv, bxr, bxg);

    // 4) wtmp = tanh(xw @ decay_w1) (2048 x 64, K=2048) f32
    sgemm<32,32,16,2,2,2><<<dim3(DDEC/32, BT/32), 256, 0, stream>>>(fA, decay_w1,
        wtmp, BT, DDEC, CC, CC, DDEC, DDEC, nullptr);

    // 5) decay = exp(-exp(wtmp @ decay_w2 + time_decay))  (K=64) -> fB
    sgemm<128,128,16,8,8,3><<<dim3(CC/128, BT/128), 256, 0, stream>>>(wtmp,
        decay_w2, fB, BT, CC, DDEC, DDEC, CC, CC, time_decay);

    // 6) r/k/v/g GEMMs, z-batched (1024 blocks -> ~4 blocks/CU)
    mm_bf16_b4<<<dim3(CC/128, BT/128, 4), 256, 0, stream>>>(
        bxr, bxk, bxv, bxg, WrT, WkT, WvT, WgT, fC, fD, fE, fF, CC);

    // 7) WKV chunked scan: summaries -> boundary scan -> outputs (y -> fA)
    wkv_chunk_summary<<<BB*HH*NCH, 256, 0, stream>>>(fD, fE, fB, Bc, cpf);
    wkv_chunk_scan<<<BB*HH, 256, 0, stream>>>(wkv_state, Bc, cpf, Sc);
    wkv_chunk_out<<<BB*HH*NCH, 256, 0, stream>>>(fC, fD, fE, fB, time_faaaa,
                                                 Sc, fA);

    // 8) groupnorm + gate -> bf16 yg
    gnorm_kernel<<<BB*TT*HH/4, 256, 0, stream>>>(fA, fF, ln_g, ln_b, byg);

    // 9) out = yg @ Wo (128x64 tile -> 512 blocks)
    mm_bf16<64,0><<<dim3(CC/64, BT/128), 256, 0, stream>>>(byg, WoT, out, CC, CC);
}

// Round 5
// 592.351 us; speedup vs baseline: 3.8057x; 1.1688x over previous
//
#include <hip/hip_runtime.h>
#include <hip/hip_bf16.h>
#include <cstdint>
#include <cstddef>

// Problem constants (B,T,C,H) = (4,512,2048,32), N=64
#define BB 4
#define TT 512
#define CC 2048
#define HH 32
#define NN 64
#define BT (BB*TT)     // 2048 rows for all GEMMs
#define DMIX 32
#define DDEC 64
#define CH 64          // wkv chunk length
#define NCH (TT/CH)    // 8 chunks
static constexpr float EPSV = 1e-5f * 64.0f;  // 1e-5 * 8^2

typedef __attribute__((ext_vector_type(8))) short bf16x8;
typedef __attribute__((ext_vector_type(4))) float f32x4;

// ---------------------------------------------------------------------------
// async global->LDS, 16B per lane: lane i lands at lds_base + i*16.
// ---------------------------------------------------------------------------
__device__ __forceinline__ void gload16(const void* g, void* l) {
    __builtin_amdgcn_global_load_lds(
        (const __attribute__((address_space(1))) unsigned int*)g,
        (__attribute__((address_space(3))) unsigned int*)l, 16, 0, 0);
}

// ---------------------------------------------------------------------------
// bf16 MFMA GEMM core, 2-phase double-buffered (T3-minimum recipe):
// stage tile k+1 (async gload_lds) BEFORE computing tile k; one
// __syncthreads per iter performs the vmcnt/lgkm drain + barrier.
// 128 x BN tile, BK=32, 4 waves (2x2). A: MxK row-major bf16 (lda).
// Bt: NxK row-major bf16 (ldb). C: f32 row-major (ldc). epi: 0=none,1=silu.
// ---------------------------------------------------------------------------
template<int BN>
__device__ __forceinline__
void mm_core(const __hip_bfloat16* __restrict__ A, const __hip_bfloat16* __restrict__ Bt,
             float* __restrict__ C, int K, int lda, int ldb, int ldc, int epi,
             int bx, int by)
{
    constexpr int NF = BN/32;                 // frags per wave in N
    __shared__ __hip_bfloat16 As[2][128][32];
    __shared__ __hip_bfloat16 Bs[2][BN][32];
    const int tid = threadIdx.x, wid = tid >> 6, lane = tid & 63;
    const int m0 = by * 128, n0 = bx * BN;
    const int wr = wid >> 1, wc = wid & 1;

    f32x4 acc[4][NF] = {};

    const int srow = wid*16 + (lane >> 2);
    const int scol = (lane & 3) * 8;
    const __hip_bfloat16* aSrc = A  + (size_t)(m0 + srow)*lda + scol;
    const __hip_bfloat16* bSrc = Bt + (size_t)(n0 + srow)*ldb + scol;

    const int fr = lane & 15;
    const int kg = (lane >> 4) * 8;

    // prologue: stage tile 0 into buf 0
    gload16(aSrc,                    &As[0][wid*16][0]);
    gload16(aSrc + (size_t)64*lda,   &As[0][64 + wid*16][0]);
    gload16(bSrc,                    &Bs[0][wid*16][0]);
    if constexpr (BN == 128)
        gload16(bSrc + (size_t)64*ldb, &Bs[0][64 + wid*16][0]);
    __syncthreads();

    int cur = 0;
    for (int k0 = 0; k0 < K; k0 += 32) {
        if (k0 + 32 < K) {              // stage next tile while computing
            gload16(aSrc + k0 + 32,                  &As[cur^1][wid*16][0]);
            gload16(aSrc + (size_t)64*lda + k0 + 32, &As[cur^1][64 + wid*16][0]);
            gload16(bSrc + k0 + 32,                  &Bs[cur^1][wid*16][0]);
            if constexpr (BN == 128)
                gload16(bSrc + (size_t)64*ldb + k0 + 32, &Bs[cur^1][64 + wid*16][0]);
        }
        bf16x8 af[4], bf[NF];
#pragma unroll
        for (int m = 0; m < 4; ++m)
            af[m] = *(const bf16x8*)&As[cur][wr*64 + m*16 + fr][kg];
#pragma unroll
        for (int n = 0; n < NF; ++n)
            bf[n] = *(const bf16x8*)&Bs[cur][wc*(BN/2) + n*16 + fr][kg];
#pragma unroll
        for (int m = 0; m < 4; ++m)
#pragma unroll
            for (int n = 0; n < NF; ++n)
                acc[m][n] = __builtin_amdgcn_mfma_f32_16x16x32_bf16(
                                af[m], bf[n], acc[m][n], 0, 0, 0);
        __syncthreads();                // drains next-tile loads + barrier
        cur ^= 1;
    }

    // C/D layout: col = lane&15, row = (lane>>4)*4 + reg   [m89]
    const int rg = (lane >> 4) * 4;
#pragma unroll
    for (int m = 0; m < 4; ++m) {
#pragma unroll
        for (int n = 0; n < NF; ++n) {
#pragma unroll
            for (int rI = 0; rI < 4; ++rI) {
                int row = m0 + wr*64 + m*16 + rg + rI;
                int col = n0 + wc*(BN/2) + n*16 + fr;
                float v = acc[m][n][rI];
                if (epi == 1) v = v / (1.f + expf(-v));
                C[(size_t)row*ldc + col] = v;
            }
        }
    }
}

template<int BN, int EPI>
__global__ __launch_bounds__(256)
void mm_bf16(const __hip_bfloat16* __restrict__ A, const __hip_bfloat16* __restrict__ Bt,
             float* __restrict__ C, int K, int ldc)
{
    mm_core<BN>(A, Bt, C, K, K, K, ldc, EPI, blockIdx.x, blockIdx.y);
}

// z-batched: 4 independent GEMMs (r,k,v,g), z==3 applies silu.
__global__ __launch_bounds__(256)
void mm_bf16_b4(const __hip_bfloat16* A0, const __hip_bfloat16* A1,
                const __hip_bfloat16* A2, const __hip_bfloat16* A3,
                const __hip_bfloat16* B0, const __hip_bfloat16* B1,
                const __hip_bfloat16* B2, const __hip_bfloat16* B3,
                float* C0, float* C1, float* C2, float* C3, int K)
{
    int z = blockIdx.z;
    const __hip_bfloat16* A = (z==0)?A0:(z==1)?A1:(z==2)?A2:A3;
    const __hip_bfloat16* B = (z==0)?B0:(z==1)?B1:(z==2)?B2:B3;
    float* C = (z==0)?C0:(z==1)?C1:(z==2)?C2:C3;
    mm_core<128>(A, B, C, K, CC, CC, CC, (z==3)?1:0, blockIdx.x, blockIdx.y);
}

// split-K (z=4, K=512 each) for the xxx GEMM; partials, no epilogue.
__global__ __launch_bounds__(256)
void mm_xxx(const __hip_bfloat16* __restrict__ A, const __hip_bfloat16* __restrict__ Bt,
            float* __restrict__ Cp)
{
    int z = blockIdx.z;
    mm_core<64>(A + z*512, Bt + z*512, Cp + (size_t)z*BT*192,
                512, CC, CC, 192, 0, blockIdx.x, blockIdx.y);
}

// dst[i] = tanh(sum_p src[i + p*seg])
__global__ __launch_bounds__(256)
void reduce_tanh_kernel(const float* __restrict__ src, float* __restrict__ dst,
                        int n, int parts, int seg)
{
    int i = blockIdx.x*256 + threadIdx.x;
    if (i < n) {
        float s = 0.f;
        for (int p = 0; p < parts; ++p) s += src[i + (size_t)p*seg];
        dst[i] = tanhf(s);
    }
}

// ---------------------------------------------------------------------------
// Weight transpose + cast: W[K][N] f32 -> Wt[N][K] bf16. 64x64 tiles.
// ---------------------------------------------------------------------------
__global__ __launch_bounds__(256)
void transpose_cast(const float* __restrict__ W, __hip_bfloat16* __restrict__ Wt,
                    int K, int N)
{
    __shared__ float tile[64][65];
    const int kb = blockIdx.y * 64, nb = blockIdx.x * 64;
    const int tr = threadIdx.x >> 6, tc = threadIdx.x & 63;
#pragma unroll
    for (int p = 0; p < 16; ++p)
        tile[tr + p*4][tc] = W[(size_t)(kb + tr + p*4)*N + nb + tc];
    __syncthreads();
#pragma unroll
    for (int p = 0; p < 16; ++p)
        Wt[(size_t)(nb + tr + p*4)*K + kb + tc] =
            __float2bfloat16(tile[tc][tr + p*4]);
}

__global__ __launch_bounds__(256)
void transpose_cast_pad(const float* __restrict__ W, __hip_bfloat16* __restrict__ Wt,
                        int K, int Nsrc)
{
    __shared__ float tile[64][65];
    const int kb = blockIdx.y * 64, nb = blockIdx.x * 64;
    const int tr = threadIdx.x >> 6, tc = threadIdx.x & 63;
#pragma unroll
    for (int p = 0; p < 16; ++p) {
        int col = nb + tc;
        tile[tr + p*4][tc] = (col < Nsrc) ?
            W[(size_t)(kb + tr + p*4)*Nsrc + col] : 0.f;
    }
    __syncthreads();
#pragma unroll
    for (int p = 0; p < 16; ++p)
        Wt[(size_t)(nb + tr + p*4)*K + kb + tc] =
            __float2bfloat16(tile[tc][tr + p*4]);
}

// ---------------------------------------------------------------------------
// Generic f32 SGEMM (decay2). EPI: 3 = exp(-exp(v + bias[n]))
// ---------------------------------------------------------------------------
template<int BM,int BN,int BK,int TM,int TN,int EPI>
__global__ __launch_bounds__((BM/TM)*(BN/TN))
void sgemm(const float* __restrict__ A, const float* __restrict__ B,
           float* __restrict__ Cd, int M, int N, int K,
           int lda, int ldb, int ldc, const float* __restrict__ bias)
{
    constexpr int NT = (BM/TM)*(BN/TN);
    __shared__ float As[BK][BM + 4];
    __shared__ float Bs[BK][BN];
    const int tid = threadIdx.x;
    const int m0 = blockIdx.y * BM;
    const int n0 = blockIdx.x * BN;
    const int rm = tid / (BN/TN);
    const int rn = tid % (BN/TN);

    float acc[TM][TN];
#pragma unroll
    for (int i = 0; i < TM; ++i)
#pragma unroll
        for (int j = 0; j < TN; ++j) acc[i][j] = 0.f;

    for (int k0 = 0; k0 < K; k0 += BK) {
#pragma unroll
        for (int p = 0; p < (BM*BK)/NT; ++p) {
            int i  = tid + p*NT;
            int m  = i / BK, kk = i % BK;
            As[kk][m] = A[(size_t)(m0+m)*lda + (k0+kk)];
        }
#pragma unroll
        for (int p = 0; p < (BK*BN)/NT; ++p) {
            int i  = tid + p*NT;
            int kk = i / BN, n = i % BN;
            Bs[kk][n] = B[(size_t)(k0+kk)*ldb + (n0+n)];
        }
        __syncthreads();
#pragma unroll
        for (int kk = 0; kk < BK; ++kk) {
            float a[TM], bb[TN];
#pragma unroll
            for (int i = 0; i < TM; ++i) a[i] = As[kk][rm*TM+i];
#pragma unroll
            for (int j = 0; j < TN; ++j) bb[j] = Bs[kk][rn*TN+j];
#pragma unroll
            for (int i = 0; i < TM; ++i)
#pragma unroll
                for (int j = 0; j < TN; ++j)
                    acc[i][j] = fmaf(a[i], bb[j], acc[i][j]);
        }
        __syncthreads();
    }

#pragma unroll
    for (int i = 0; i < TM; ++i) {
        int m = m0 + rm*TM + i;
#pragma unroll
        for (int j = 0; j < TN; ++j) {
            int n = n0 + rn*TN + j;
            float v = acc[i][j];
            if constexpr (EPI == 3) { v = expf(-expf(v + bias[n])); }
            Cd[(size_t)m*ldc + n] = v;
        }
    }
}

// ---------------------------------------------------------------------------
// decay1 split-K partials: dpart[kz][m][n] = xw[m, kz*128..+128) @ w1[.., n]
// grid (M/64, 16). LDS 64KB.
// ---------------------------------------------------------------------------
__global__ __launch_bounds__(256)
void decay1_partial(const float* __restrict__ xw, const float* __restrict__ w1,
                    float* __restrict__ dpart)
{
    __shared__ float As[64][128];
    __shared__ float Bs[128][64];
    const int m0 = blockIdx.x * 64;
    const int k0 = blockIdx.y * 128;
    const int tid = threadIdx.x;
#pragma unroll
    for (int p = 0; p < 8; ++p) {
        int f4 = tid + p*256;
        int m = f4 >> 5, kq = (f4 & 31)*4;
        *(float4*)&As[m][kq] = *(const float4*)(xw + (size_t)(m0+m)*CC + k0 + kq);
    }
#pragma unroll
    for (int p = 0; p < 8; ++p) {
        int f4 = tid + p*256;
        int kk = f4 >> 4, nq = (f4 & 15)*4;
        *(float4*)&Bs[kk][nq] = *(const float4*)(w1 + (size_t)(k0+kk)*DDEC + nq);
    }
    __syncthreads();
    const int n = tid & 63, mq = tid >> 6;
    float acc[16] = {};
#pragma unroll 4
    for (int kk = 0; kk < 128; ++kk) {
        float b = Bs[kk][n];
#pragma unroll
        for (int r = 0; r < 16; ++r)
            acc[r] = fmaf(As[mq*16 + r][kk], b, acc[r]);
    }
    float* o = dpart + (size_t)blockIdx.y*BT*DDEC + (size_t)m0*DDEC;
#pragma unroll
    for (int r = 0; r < 16; ++r)
        o[(size_t)(mq*16 + r)*DDEC + n] = acc[r];
}

// ---------------------------------------------------------------------------
// Prep: dxprev = shifted(x) - x (f32); xin = x + dxprev*maa_x as bf16.
// ---------------------------------------------------------------------------
__global__ __launch_bounds__(256)
void prep_kernel(const float* __restrict__ x, const float* __restrict__ shift,
                 const float* __restrict__ maa_x,
                 float* __restrict__ dxprev, __hip_bfloat16* __restrict__ xin)
{
    size_t idx = (size_t)blockIdx.x*256 + threadIdx.x;
    int c = (int)(idx % CC);
    size_t bt = idx / CC;
    int t = (int)(bt % TT);
    int b = (int)(bt / TT);
    float xv = x[idx];
    float prev = t ? x[idx - CC] : shift[(size_t)b*CC + c];
    float dx = prev - xv;
    dxprev[idx] = dx;
    xin[idx] = __float2bfloat16(fmaf(dx, maa_x[c], xv));
}

// ---------------------------------------------------------------------------
// Fused: mix_f = xxx[:,f,:] @ maa_w2[f] (K=32 each, xxx ld=192), then
// xf = x + dx*(maa_f + mix_f). xw f32 (in-place over dx), others bf16.
// ---------------------------------------------------------------------------
__global__ __launch_bounds__(256)
void fusedmix_kernel(const float* __restrict__ xxx, const float* __restrict__ w2,
                     const float* __restrict__ x, const float* dx,
                     const float* __restrict__ maa_w, const float* __restrict__ maa_k,
                     const float* __restrict__ maa_v, const float* __restrict__ maa_r,
                     const float* __restrict__ maa_g,
                     float* xw, __hip_bfloat16* __restrict__ xk,
                     __hip_bfloat16* __restrict__ xv2, __hip_bfloat16* __restrict__ xr,
                     __hip_bfloat16* __restrict__ xg)
{
    __shared__ float w2s[160][64];
    const int c0 = blockIdx.x * 64, bt0 = blockIdx.y * 128;
    const int tid = threadIdx.x;
    const int tc = tid & 63, tb = tid >> 6;
    for (int idx = tid; idx < 160*64; idx += 256) {
        int kk = idx >> 6, cc = idx & 63;
        w2s[kk][cc] = w2[(size_t)kk*CC + c0 + cc];
    }
    __syncthreads();
    const int c = c0 + tc;
    const float mw_c = maa_w[c], mk_c = maa_k[c], mv_c = maa_v[c];
    const float mr_c = maa_r[c], mg_c = maa_g[c];
    for (int it = 0; it < 32; ++it) {
        int bt = bt0 + it*4 + tb;
        const float* xrow = xxx + (size_t)bt*192;
        float a0=0,a1=0,a2=0,a3=0,a4=0;
#pragma unroll
        for (int d2 = 0; d2 < 32; ++d2) {
            a0 = fmaf(xrow[d2],       w2s[d2][tc],       a0);
            a1 = fmaf(xrow[32+d2],    w2s[32+d2][tc],    a1);
            a2 = fmaf(xrow[64+d2],    w2s[64+d2][tc],    a2);
            a3 = fmaf(xrow[96+d2],    w2s[96+d2][tc],    a3);
            a4 = fmaf(xrow[128+d2],   w2s[128+d2][tc],   a4);
        }
        size_t idx = (size_t)bt*CC + c;
        float xval = x[idx], dv = dx[idx];
        xw[idx]  = fmaf(dv, mw_c + a0, xval);
        xk[idx]  = __float2bfloat16(fmaf(dv, mk_c + a1, xval));
        xv2[idx] = __float2bfloat16(fmaf(dv, mv_c + a2, xval));
        xr[idx]  = __float2bfloat16(fmaf(dv, mr_c + a3, xval));
        xg[idx]  = __float2bfloat16(fmaf(dv, mg_c + a4, xval));
    }
}

// ---------------------------------------------------------------------------
// WKV6 chunked scan.
// K0 (wkv_prep): per (bh,chunk): cpe = prefix-prod of d; overwrite IN PLACE
//   r -> q~ = r*cpe ; k -> kh2 = k/cpe_next ; write cpf (full chunk prod)
//   and diag_t = sum_i r*u*k. 4-segment parallel scan; diag by wave shfl.
// K1: Bc[i][j] = cpf[i] * sum_t kh2[t][i] * v[t][j]   (pure 64x64x64)
// K2: boundary scan S_{c+1} = cpf .* S_c + Bc; stores S_c.
// K3: Y = masked(q~ kh2^T, diag) @ V + q~ @ S_c       (two 64x64x64)
// ---------------------------------------------------------------------------
__global__ __launch_bounds__(256)
void wkv_prep(float* __restrict__ r, float* __restrict__ k,
              const float* __restrict__ d, const float* __restrict__ u,
              float* __restrict__ cpf, float* __restrict__ diagG)
{
    __shared__ float rs[64][68], ks[64][68], ds[64][68];
    __shared__ float pp[4][64];
    const int task = blockIdx.x;
    const int bh = task >> 3, c = task & 7;
    const int b = bh >> 5, h = bh & 31;
    const int tid = threadIdx.x;
    const size_t base = ((size_t)b*TT + c*CH)*CC + (size_t)h*NN;

#pragma unroll
    for (int p = 0; p < 4; ++p) {
        int f4 = tid + p*256;
        int t = f4 >> 4, i4 = (f4 & 15)*4;
        *(float4*)&rs[t][i4] = *(const float4*)(r + base + (size_t)t*CC + i4);
        *(float4*)&ks[t][i4] = *(const float4*)(k + base + (size_t)t*CC + i4);
        *(float4*)&ds[t][i4] = *(const float4*)(d + base + (size_t)t*CC + i4);
    }
    __syncthreads();

    const int i = tid & 63, qd = tid >> 6;   // wave qd handles t in [16qd,16qd+16)
    float p1 = 1.f;
#pragma unroll
    for (int tt = 0; tt < 16; ++tt) p1 *= ds[qd*16 + tt][i];
    pp[qd][i] = p1;
    __syncthreads();

    float pcur = 1.f;
    for (int q = 0; q < 3; ++q) if (q < qd) pcur *= pp[q][i];   // uniform branch
    const float ui = u[h*NN + i];
#pragma unroll
    for (int tt = 0; tt < 16; ++tt) {
        int t = qd*16 + tt;
        float rv = rs[t][i], kv = ks[t][i], dv = ds[t][i];
        float q_ = rv * pcur;
        float pd = pcur * dv;
        float kh = kv * __builtin_amdgcn_rcpf(pd);
        rs[t][i] = q_;
        ks[t][i] = kh;
        float contrib = q_ * ui * kh * dv;   // == r*u*k
#pragma unroll
        for (int m = 1; m < 64; m <<= 1) contrib += __shfl_xor(contrib, m, 64);
        if (i == 0) diagG[(size_t)task*64 + t] = contrib;
        pcur = pd;
    }
    if (qd == 3) cpf[(size_t)task*64 + i] = pcur;
    __syncthreads();

#pragma unroll
    for (int p = 0; p < 4; ++p) {
        int f4 = tid + p*256;
        int t = f4 >> 4, i4 = (f4 & 15)*4;
        *(float4*)(r + base + (size_t)t*CC + i4) = *(float4*)&rs[t][i4];
        *(float4*)(k + base + (size_t)t*CC + i4) = *(float4*)&ks[t][i4];
    }
}

__global__ __launch_bounds__(256)
void wkv_chunk_summary(const float* __restrict__ kh2, const float* __restrict__ v,
                       const float* __restrict__ cpf, float* __restrict__ Bc)
{
    __shared__ float ks[64][64];
    __shared__ float vs[64][64];
    const int task = blockIdx.x;
    const int bh = task >> 3, c = task & 7;
    const int b = bh >> 5, h = bh & 31;
    const int tid = threadIdx.x;
    const size_t base = ((size_t)b*TT + c*CH)*CC + (size_t)h*NN;
#pragma unroll
    for (int p = 0; p < 4; ++p) {
        int f4 = tid + p*256;
        int t = f4 >> 4, j4 = (f4 & 15)*4;
        *(float4*)&ks[t][j4] = *(const float4*)(kh2 + base + (size_t)t*CC + j4);
        *(float4*)&vs[t][j4] = *(const float4*)(v   + base + (size_t)t*CC + j4);
    }
    __syncthreads();

    const int i0 = (tid >> 4)*4, j0 = (tid & 15)*4;
    float acc[4][4] = {};
#pragma unroll 4
    for (int t = 0; t < 64; ++t) {
        float4 m = *(const float4*)&ks[t][i0];
        float4 n = *(const float4*)&vs[t][j0];
        acc[0][0] = fmaf(m.x,n.x,acc[0][0]); acc[0][1] = fmaf(m.x,n.y,acc[0][1]);
        acc[0][2] = fmaf(m.x,n.z,acc[0][2]); acc[0][3] = fmaf(m.x,n.w,acc[0][3]);
        acc[1][0] = fmaf(m.y,n.x,acc[1][0]); acc[1][1] = fmaf(m.y,n.y,acc[1][1]);
        acc[1][2] = fmaf(m.y,n.z,acc[1][2]); acc[1][3] = fmaf(m.y,n.w,acc[1][3]);
        acc[2][0] = fmaf(m.z,n.x,acc[2][0]); acc[2][1] = fmaf(m.z,n.y,acc[2][1]);
        acc[2][2] = fmaf(m.z,n.z,acc[2][2]); acc[2][3] = fmaf(m.z,n.w,acc[2][3]);
        acc[3][0] = fmaf(m.w,n.x,acc[3][0]); acc[3][1] = fmaf(m.w,n.y,acc[3][1]);
        acc[3][2] = fmaf(m.w,n.z,acc[3][2]); acc[3][3] = fmaf(m.w,n.w,acc[3][3]);
    }
    const float* cp = cpf + (size_t)task*64;
    float* Bg = Bc + (size_t)task*4096;
#pragma unroll
    for (int a4 = 0; a4 < 4; ++a4) {
        float sc = cp[i0 + a4];
        *(float4*)&Bg[(i0+a4)*64 + j0] =
            make_float4(acc[a4][0]*sc, acc[a4][1]*sc, acc[a4][2]*sc, acc[a4][3]*sc);
    }
}

__global__ __launch_bounds__(256)
void wkv_chunk_scan(const float* __restrict__ s0, const float* __restrict__ Bc,
                    const float* __restrict__ cpf, float* __restrict__ Sc)
{
    const int bh = blockIdx.x, tid = threadIdx.x;
    float S[16];
    const float* sp = s0 + (size_t)bh*4096;
#pragma unroll
    for (int p = 0; p < 16; ++p) S[p] = sp[p*256 + tid];
    for (int c = 0; c < NCH; ++c) {
        const size_t tk = (size_t)bh*NCH + c;
        const float* B  = Bc  + tk*4096;
        const float* cp = cpf + tk*64;
        float* so = Sc + tk*4096;
#pragma unroll
        for (int p = 0; p < 16; ++p) {
            int e = p*256 + tid;
            so[e] = S[p];
            S[p] = fmaf(cp[e >> 6], S[p], B[e]);
        }
    }
}

__global__ __launch_bounds__(256)
void wkv_chunk_out(const float* __restrict__ q_, const float* __restrict__ kh2,
                   const float* __restrict__ v, const float* __restrict__ diagG,
                   const float* __restrict__ Sc, float* __restrict__ y)
{
    __shared__ float qsT[64][68];     // q~^T : [i][t]
    __shared__ float ktsT[64][68];    // kh2^T : [i][t], later AT[t'][t]
    __shared__ float vs[64][64];
    __shared__ float Ss[64][64];
    __shared__ float diag[64];
    const int task = blockIdx.x;
    const int bh = task >> 3, c = task & 7;
    const int b = bh >> 5, h = bh & 31;
    const int tid = threadIdx.x;
    const size_t base = ((size_t)b*TT + c*CH)*CC + (size_t)h*NN;

    // transpose-gather q~ and kh2 into [i][t] (coalesced over i per t)
    const int i = tid & 63, tg = tid >> 6;
#pragma unroll
    for (int s = 0; s < 4; ++s) {
        int tb = (s*4 + tg)*4;
        float4 qv, kv;
        qv.x = q_[base + (size_t)(tb+0)*CC + i];
        qv.y = q_[base + (size_t)(tb+1)*CC + i];
        qv.z = q_[base + (size_t)(tb+2)*CC + i];
        qv.w = q_[base + (size_t)(tb+3)*CC + i];
        *(float4*)&qsT[i][tb] = qv;
        kv.x = kh2[base + (size_t)(tb+0)*CC + i];
        kv.y = kh2[base + (size_t)(tb+1)*CC + i];
        kv.z = kh2[base + (size_t)(tb+2)*CC + i];
        kv.w = kh2[base + (size_t)(tb+3)*CC + i];
        *(float4*)&ktsT[i][tb] = kv;
    }
#pragma unroll
    for (int p = 0; p < 4; ++p) {
        int f4 = tid + p*256;
        int t = f4 >> 4, j4 = (f4 & 15)*4;
        *(float4*)&vs[t][j4] = *(const float4*)(v + base + (size_t)t*CC + j4);
        *(float4*)&Ss[t][j4] = *(const float4*)(Sc + (size_t)task*4096 + (size_t)t*64 + j4);
    }
    if (tid < 64) diag[tid] = diagG[(size_t)task*64 + tid];
    __syncthreads();

    // A-stage: AT[t'][t] = sum_i kh2[t'][i] * q~[t][i]
    const int t0  = (tid & 15)*4;
    const int tp0 = (tid >> 4)*4;
    float a[4][4] = {};
#pragma unroll 4
    for (int ii = 0; ii < 64; ++ii) {
        float4 m = *(const float4*)&ktsT[ii][tp0];
        float4 n = *(const float4*)&qsT[ii][t0];
        a[0][0] = fmaf(m.x,n.x,a[0][0]); a[0][1] = fmaf(m.x,n.y,a[0][1]);
        a[0][2] = fmaf(m.x,n.z,a[0][2]); a[0][3] = fmaf(m.x,n.w,a[0][3]);
        a[1][0] = fmaf(m.y,n.x,a[1][0]); a[1][1] = fmaf(m.y,n.y,a[1][1]);
        a[1][2] = fmaf(m.y,n.z,a[1][2]); a[1][3] = fmaf(m.y,n.w,a[1][3]);
        a[2][0] = fmaf(m.z,n.x,a[2][0]); a[2][1] = fmaf(m.z,n.y,a[2][1]);
        a[2][2] = fmaf(m.z,n.z,a[2][2]); a[2][3] = fmaf(m.z,n.w,a[2][3]);
        a[3][0] = fmaf(m.w,n.x,a[3][0]); a[3][1] = fmaf(m.w,n.y,a[3][1]);
        a[3][2] = fmaf(m.w,n.z,a[3][2]); a[3][3] = fmaf(m.w,n.w,a[3][3]);
    }
    float am[4][4];
#pragma unroll
    for (int a4 = 0; a4 < 4; ++a4)
#pragma unroll
        for (int b4 = 0; b4 < 4; ++b4) {
            int tp = tp0 + a4, t = t0 + b4;
            am[a4][b4] = (tp < t) ? a[a4][b4] : (tp == t ? diag[t] : 0.f);
        }
    __syncthreads();
#pragma unroll
    for (int a4 = 0; a4 < 4; ++a4)
#pragma unroll
        for (int b4 = 0; b4 < 4; ++b4)
            ktsT[tp0 + a4][t0 + b4] = am[a4][b4];   // ktsT now holds AT
    __syncthreads();

    // Y-stage
    const int j0 = (tid & 15)*4;
    const int y0 = (tid >> 4)*4;
    float acc[4][4] = {};
#pragma unroll 4
    for (int kk = 0; kk < 64; ++kk) {
        float4 m = *(const float4*)&ktsT[kk][y0];
        float4 n = *(const float4*)&vs[kk][j0];
        acc[0][0] = fmaf(m.x,n.x,acc[0][0]); acc[0][1] = fmaf(m.x,n.y,acc[0][1]);
        acc[0][2] = fmaf(m.x,n.z,acc[0][2]); acc[0][3] = fmaf(m.x,n.w,acc[0][3]);
        acc[1][0] = fmaf(m.y,n.x,acc[1][0]); acc[1][1] = fmaf(m.y,n.y,acc[1][1]);
        acc[1][2] = fmaf(m.y,n.z,acc[1][2]); acc[1][3] = fmaf(m.y,n.w,acc[1][3]);
        acc[2][0] = fmaf(m.z,n.x,acc[2][0]); acc[2][1] = fmaf(m.z,n.y,acc[2][1]);
        acc[2][2] = fmaf(m.z,n.z,acc[2][2]); acc[2][3] = fmaf(m.z,n.w,acc[2][3]);
        acc[3][0] = fmaf(m.w,n.x,acc[3][0]); acc[3][1] = fmaf(m.w,n.y,acc[3][1]);
        acc[3][2] = fmaf(m.w,n.z,acc[3][2]); acc[3][3] = fmaf(m.w,n.w,acc[3][3]);
    }
#pragma unroll 4
    for (int kk = 0; kk < 64; ++kk) {
        float4 m = *(const float4*)&qsT[kk][y0];
        float4 n = *(const float4*)&Ss[kk][j0];
        acc[0][0] = fmaf(m.x,n.x,acc[0][0]); acc[0][1] = fmaf(m.x,n.y,acc[0][1]);
        acc[0][2] = fmaf(m.x,n.z,acc[0][2]); acc[0][3] = fmaf(m.x,n.w,acc[0][3]);
        acc[1][0] = fmaf(m.y,n.x,acc[1][0]); acc[1][1] = fmaf(m.y,n.y,acc[1][1]);
        acc[1][2] = fmaf(m.y,n.z,acc[1][2]); acc[1][3] = fmaf(m.y,n.w,acc[1][3]);
        acc[2][0] = fmaf(m.z,n.x,acc[2][0]); acc[2][1] = fmaf(m.z,n.y,acc[2][1]);
        acc[2][2] = fmaf(m.z,n.z,acc[2][2]); acc[2][3] = fmaf(m.z,n.w,acc[2][3]);
        acc[3][0] = fmaf(m.w,n.x,acc[3][0]); acc[3][1] = fmaf(m.w,n.y,acc[3][1]);
        acc[3][2] = fmaf(m.w,n.z,acc[3][2]); acc[3][3] = fmaf(m.w,n.w,acc[3][3]);
    }
#pragma unroll
    for (int a4 = 0; a4 < 4; ++a4)
        *(float4*)(y + base + (size_t)(y0 + a4)*CC + j0) =
            make_float4(acc[a4][0], acc[a4][1], acc[a4][2], acc[a4][3]);
}

// ---------------------------------------------------------------------------
// GroupNorm over N=64 per (b,t,h) + affine + gate; emits bf16 for Wo GEMM.
// ---------------------------------------------------------------------------
__global__ __launch_bounds__(256)
void gnorm_kernel(const float* __restrict__ y, const float* __restrict__ g,
                  const float* __restrict__ ln_g, const float* __restrict__ ln_b,
                  __hip_bfloat16* __restrict__ yg)
{
    int gidx = blockIdx.x*4 + (threadIdx.x >> 6);
    int lane = threadIdx.x & 63;
    int h = gidx % HH;
    int bt = gidx / HH;
    size_t idx = (size_t)bt*CC + (size_t)h*NN + lane;

    float val = y[idx];
    float sum = val, sq = val*val;
#pragma unroll
    for (int m = 1; m < 64; m <<= 1) {
        sum += __shfl_xor(sum, m, 64);
        sq  += __shfl_xor(sq,  m, 64);
    }
    float mean = sum * (1.f/64.f);
    float var  = sq  * (1.f/64.f) - mean*mean;
    float nv = (val - mean) * rsqrtf(var + EPSV);
    int c = h*NN + lane;
    yg[idx] = __float2bfloat16((nv * ln_g[c] + ln_b[c]) * g[idx]);
}

__global__ __launch_bounds__(256)
void shiftout_kernel(const float* __restrict__ x, float* __restrict__ o)
{
    int i = blockIdx.x*256 + threadIdx.x;  // B*C = 8192
    int b = i / CC, c = i % CC;
    o[i] = x[((size_t)b*TT + (TT-1))*CC + c];
}

// ---------------------------------------------------------------------------
extern "C" void kernel_launch(void* const* d_in, const int* in_sizes, int n_in,
                              void* d_out, int out_size, void* d_ws, size_t ws_size,
                              hipStream_t stream)
{
    const float* x          = (const float*)d_in[0];
    const float* shift_st   = (const float*)d_in[1];
    const float* wkv_state  = (const float*)d_in[2];
    const float* maa_x      = (const float*)d_in[3];
    const float* maa_w      = (const float*)d_in[4];
    const float* maa_k      = (const float*)d_in[5];
    const float* maa_v      = (const float*)d_in[6];
    const float* maa_r      = (const float*)d_in[7];
    const float* maa_g      = (const float*)d_in[8];
    const float* maa_w1     = (const float*)d_in[9];
    const float* maa_w2     = (const float*)d_in[10];
    const float* time_decay = (const float*)d_in[11];
    const float* decay_w1   = (const float*)d_in[12];
    const float* decay_w2   = (const float*)d_in[13];
    const float* time_faaaa = (const float*)d_in[14];
    const float* Wr         = (const float*)d_in[15];
    const float* Wk         = (const float*)d_in[16];
    const float* Wv         = (const float*)d_in[17];
    const float* Wg         = (const float*)d_in[18];
    const float* Wo         = (const float*)d_in[19];
    const float* ln_g       = (const float*)d_in[20];
    const float* ln_b       = (const float*)d_in[21];

    // f32 slots (16.78 MB each):
    //   fA: dxprev -> xw -> Bc -> y     fB: decay
    //   fC: r -> q~   fD: k -> kh2   fE: v   fF: g
    float* ws = (float*)d_ws;
    const size_t SL = (size_t)BT*CC;
    float* fA = ws;
    float* fB = fA + SL;
    float* fC = fB + SL;
    float* fD = fC + SL;
    float* fE = fD + SL;
    float* fF = fE + SL;
    float* xxxp  = fF + SL;                        // 4 x BT*192 partials
    float* xxx   = xxxp + (size_t)4*BT*192;        // BT*192
    float* wtmp  = xxx + (size_t)BT*192;           // BT*64
    float* dpart = wtmp + (size_t)BT*DDEC;         // 16 x BT*64
    float* cpf   = dpart + (size_t)16*BT*DDEC;     // 1024*64
    float* diagG = cpf + (size_t)1024*64;          // 1024*64
    // bf16 region
    __hip_bfloat16* hbase = (__hip_bfloat16*)(diagG + (size_t)1024*64);
    const size_t HL = (size_t)CC*CC;
    __hip_bfloat16* WrT  = hbase;
    __hip_bfloat16* WkT  = WrT + HL;
    __hip_bfloat16* WvT  = WkT + HL;
    __hip_bfloat16* WgT  = WvT + HL;
    __hip_bfloat16* WoT  = WgT + HL;
    __hip_bfloat16* bxr  = WoT + HL;
    __hip_bfloat16* bxk  = bxr + HL;
    __hip_bfloat16* bxv  = bxk + HL;
    __hip_bfloat16* bxg  = bxv + HL;
    __hip_bfloat16* byg  = bxg + HL;
    __hip_bfloat16* bxin = byg + HL;
    __hip_bfloat16* W1Tp = bxin + HL;              // 192 x 2048 bf16 (zero-padded)

    // chunk scratch aliases:
    float* Bc = fA;               // xw dead after decay1; y overwrites later
    float* Sc = (float*)byg;      // byg+bxin dead until gnorm

    float* out       = (float*)d_out;
    float* out_shift = out + SL;
    float* out_state = out_shift + (size_t)BB*CC;

    const int EW_GRID = (int)(SL/256);
    dim3 tg(CC/64, CC/64);

    // 0) weight transposes
    transpose_cast<<<tg, 256, 0, stream>>>(Wr, WrT, CC, CC);
    transpose_cast<<<tg, 256, 0, stream>>>(Wk, WkT, CC, CC);
    transpose_cast<<<tg, 256, 0, stream>>>(Wv, WvT, CC, CC);
    transpose_cast<<<tg, 256, 0, stream>>>(Wg, WgT, CC, CC);
    transpose_cast<<<tg, 256, 0, stream>>>(Wo, WoT, CC, CC);
    transpose_cast_pad<<<dim3(3, CC/64), 256, 0, stream>>>(maa_w1, W1Tp, CC, 160);

    // 1) prep + trivial outputs
    prep_kernel<<<EW_GRID, 256, 0, stream>>>(x, shift_st, maa_x, fA, bxin);
    shiftout_kernel<<<BB*CC/256, 256, 0, stream>>>(x, out_shift);
    hipMemcpyAsync(out_state, wkv_state, (size_t)BB*HH*NN*NN*sizeof(float),
                   hipMemcpyDeviceToDevice, stream);

    // 2) xxx partials (split-K z=4), then reduce+tanh
    mm_xxx<<<dim3(3, BT/128, 4), 256, 0, stream>>>(bxin, W1Tp, xxxp);
    reduce_tanh_kernel<<<(BT*192)/256, 256, 0, stream>>>(xxxp, xxx,
        BT*192, 4, BT*192);

    // 3) fused mix (xw f32 into fA in-place; xk/xv/xr/xg bf16)
    fusedmix_kernel<<<dim3(CC/64, BT/128), 256, 0, stream>>>(xxx, maa_w2, x, fA,
        maa_w, maa_k, maa_v, maa_r, maa_g, fA, bxk, bxv, bxr, bxg);

    // 4) decay1 split-K partials + reduce+tanh -> wtmp
    decay1_partial<<<dim3(BT/64, 16), 256, 0, stream>>>(fA, decay_w1, dpart);
    reduce_tanh_kernel<<<(BT*DDEC)/256, 256, 0, stream>>>(dpart, wtmp,
        BT*DDEC, 16, BT*DDEC);

    // 5) decay = exp(-exp(wtmp @ decay_w2 + time_decay))  (K=64) -> fB
    sgemm<128,128,16,8,8,3><<<dim3(CC/128, BT/128), 256, 0, stream>>>(wtmp,
        decay_w2, fB, BT, CC, DDEC, DDEC, CC, CC, time_decay);

    // 6) r/k/v/g GEMMs, z-batched, double-buffered
    mm_bf16_b4<<<dim3(CC/128, BT/128, 4), 256, 0, stream>>>(
        bxr, bxk, bxv, bxg, WrT, WkT, WvT, WgT, fC, fD, fE, fF, CC);

    // 7) WKV chunked scan
    wkv_prep<<<BB*HH*NCH, 256, 0, stream>>>(fC, fD, fB, time_faaaa, cpf, diagG);
    wkv_chunk_summary<<<BB*HH*NCH, 256, 0, stream>>>(fD, fE, cpf, Bc);
    wkv_chunk_scan<<<BB*HH, 256, 0, stream>>>(wkv_state, Bc, cpf, Sc);
    wkv_chunk_out<<<BB*HH*NCH, 256, 0, stream>>>(fC, fD, fE, diagG, Sc, fA);

    // 8) groupnorm + gate -> bf16 yg
    gnorm_kernel<<<BB*TT*HH/4, 256, 0, stream>>>(fA, fF, ln_g, ln_b, byg);

    // 9) out = yg @ Wo (128x64 tile -> 512 blocks)
    mm_bf16<64,0><<<dim3(CC/64, BT/128), 256, 0, stream>>>(byg, WoT, out, CC, CC);
}